// Round 2
// baseline (974.400 us; speedup 1.0000x reference)
//
#include <hip/hip_runtime.h>
#include <hip/hip_bf16.h>
#include <math.h>

// MGAT_24970939859571 — round 2: f32 inputs/outputs (per reference dtypes),
// bf16 workspace for q/k/v/agg. idx int32.
// B=4, N=16384 (128x128), K=16 neighbors, D=256, SD=64.

typedef unsigned short u16;

#define NB 16384
#define NROWS 65536
#define DD 256
#define SDD 64

__device__ __forceinline__ float b2f(u16 u) {
  union { unsigned int i; float f; } c; c.i = ((unsigned int)u) << 16; return c.f;
}
__device__ __forceinline__ u16 f2b(float f) {
  union { float f; unsigned int i; } c; c.f = f;
  unsigned int i = c.i;
  return (u16)((i + 0x7FFFu + ((i >> 16) & 1u)) >> 16);  // RNE
}
__device__ __forceinline__ float gelu_exact(float x) {
  return 0.5f * x * (1.0f + erff(x * 0.70710678118654752f));
}

// ---------------------------------------------------------------------------
// Per-row scalar path: S stats -> s_emb MLP, z_emb, abc, g-softmax, A terms.
// One wave (64 threads) per row.
// ---------------------------------------------------------------------------
__global__ __launch_bounds__(64) void k_scalar(
    const float* __restrict__ z, const float* __restrict__ S,
    const float* __restrict__ Ws1, const float* __restrict__ bs1,
    const float* __restrict__ Ws2, const float* __restrict__ bs2,
    const float* __restrict__ Wzg, const float* __restrict__ bzg,
    const float* __restrict__ Wph, const float* __restrict__ bph,
    const float* __restrict__ Wsg, const float* __restrict__ bsg,
    float* __restrict__ rowdat, float* __restrict__ anorm)
{
  int r = blockIdx.x;
  int t = threadIdx.x;           // 0..63 (one wave)
  __shared__ float kin[32];
  __shared__ float h1s[16];
  __shared__ float abcs[8];

  // S row stats
  float sv = S[(size_t)r * SDD + t];
  float s1 = sv, s2 = sv * sv;
  #pragma unroll
  for (int o = 32; o; o >>= 1) { s1 += __shfl_xor(s1, o); s2 += __shfl_xor(s2, o); }
  float m1 = s1 * (1.0f / 64.0f), m2 = s2 * (1.0f / 64.0f);

  // z_emb partial: lane = j + 16*grp, grp covers i-range [grp*64, grp*64+64)
  int j = t & 15, grp = t >> 4;
  const float* zr = z + (size_t)r * DD + grp * 64;
  float acc = 0.0f;
  for (int i = 0; i < 64; ++i)
    acc += zr[i] * Wzg[(grp * 64 + i) * 16 + j];
  acc += __shfl_xor(acc, 16);
  acc += __shfl_xor(acc, 32);   // all 4 groups summed

  if (t < 16) {
    float h1 = m1 * Ws1[j] + m2 * Ws1[16 + j] + bs1[j];
    h1s[j] = gelu_exact(h1);
  }
  __syncthreads();
  if (t < 16) {
    float h2 = bs2[j];
    #pragma unroll
    for (int i = 0; i < 16; ++i) h2 += h1s[i] * Ws2[i * 16 + j];
    kin[j] = gelu_exact(h2);                 // s_emb first
    kin[16 + j] = gelu_exact(acc + bzg[j]);  // z_emb second
  }
  __syncthreads();
  if (t < 6) {
    int c = t % 3;
    const float* Wp = (t < 3) ? Wph : Wsg;
    const float* bp = (t < 3) ? bph : bsg;
    float a = bp[c];
    #pragma unroll
    for (int i = 0; i < 32; ++i) a += kin[i] * Wp[i * 3 + c];
    abcs[t] = a;
  }
  __syncthreads();
  if (t == 0) {
    float La = expf(abcs[0]), Lb = abcs[1], Lc = expf(abcs[2]);
    float A00 = La * La, A01 = La * Lb, A11 = Lb * Lb + Lc * Lc;
    float g0 = abcs[3], g1 = abcs[4], g2 = abcs[5];
    float gm = fmaxf(g0, fmaxf(g1, g2));
    float e0 = expf(g0 - gm), e1 = expf(g1 - gm), e2 = expf(g2 - gm);
    float inv = 1.0f / (e0 + e1 + e2);
    float* rd = rowdat + (size_t)r * 8;
    rd[0] = A00; rd[1] = A01; rd[2] = A11;
    rd[3] = e0 * inv; rd[4] = e1 * inv; rd[5] = e2 * inv;
    anorm[r] = sqrtf(A00 * A00 + 2.0f * A01 * A01 + A11 * A11);
  }
}

// ---------------------------------------------------------------------------
// Tiled GEMM: out[M x 256] = A[M x 256] @ W[256 x 256] + bias (+ zadd).
// IN_BF16: A is bf16(u16) else f32. OUT_BF16: out bf16(u16) else f32.
// W/bias/zadd always f32. 64x64 tile, 256 threads, 4x4 micro-tile, f32 accum.
// ---------------------------------------------------------------------------
#define GT 64
#define KC 16
template<int IN_BF16, int OUT_BF16>
__global__ __launch_bounds__(256) void k_gemm(
    const void* __restrict__ Av, const float* __restrict__ W,
    const float* __restrict__ bias, const float* __restrict__ zadd,
    void* __restrict__ outv)
{
  __shared__ float As[KC][GT + 4];   // [k][m]
  __shared__ float Bs[KC][GT + 4];   // [k][n]
  int t  = threadIdx.x;
  int m0 = blockIdx.x * GT;
  int j0 = blockIdx.y * GT;
  int tx = t & 15, ty = t >> 4;
  int la_row = t >> 2;          // 0..63
  int la_col = (t & 3) * 4;     // 0,4,8,12
  int lb_row = t >> 4;          // 0..15
  int lb_col = (t & 15) * 4;    // 0..60

  float acc[4][4] = {};

  for (int kc = 0; kc < 256; kc += KC) {
    float a0, a1, a2, a3;
    if constexpr (IN_BF16) {
      const u16* A = (const u16*)Av;
      ushort4 av = *(const ushort4*)(A + (size_t)(m0 + la_row) * 256 + kc + la_col);
      a0 = b2f(av.x); a1 = b2f(av.y); a2 = b2f(av.z); a3 = b2f(av.w);
    } else {
      const float* A = (const float*)Av;
      float4 av = *(const float4*)(A + (size_t)(m0 + la_row) * 256 + kc + la_col);
      a0 = av.x; a1 = av.y; a2 = av.z; a3 = av.w;
    }
    float4 wv = *(const float4*)(W + (size_t)(kc + lb_row) * 256 + j0 + lb_col);
    __syncthreads();   // protect previous iteration's LDS reads
    As[la_col + 0][la_row] = a0;
    As[la_col + 1][la_row] = a1;
    As[la_col + 2][la_row] = a2;
    As[la_col + 3][la_row] = a3;
    *(float4*)&Bs[lb_row][lb_col] = wv;
    __syncthreads();
    #pragma unroll
    for (int kk = 0; kk < KC; ++kk) {
      float4 a4 = *(const float4*)&As[kk][ty * 4];
      float4 b4 = *(const float4*)&Bs[kk][tx * 4];
      float av4[4] = {a4.x, a4.y, a4.z, a4.w};
      float bv4[4] = {b4.x, b4.y, b4.z, b4.w};
      #pragma unroll
      for (int rr = 0; rr < 4; ++rr)
        #pragma unroll
        for (int cc = 0; cc < 4; ++cc)
          acc[rr][cc] += av4[rr] * bv4[cc];
    }
  }

  int colb = j0 + tx * 4;
  float4 bia = *(const float4*)(bias + colb);
  #pragma unroll
  for (int rr = 0; rr < 4; ++rr) {
    int row = m0 + ty * 4 + rr;
    float o0 = acc[rr][0] + bia.x;
    float o1 = acc[rr][1] + bia.y;
    float o2 = acc[rr][2] + bia.z;
    float o3 = acc[rr][3] + bia.w;
    if (zadd) {
      float4 zv = *(const float4*)(zadd + (size_t)row * 256 + colb);
      o0 += zv.x; o1 += zv.y; o2 += zv.z; o3 += zv.w;
    }
    if constexpr (OUT_BF16) {
      *(ushort4*)((u16*)outv + (size_t)row * 256 + colb) =
          make_ushort4(f2b(o0), f2b(o1), f2b(o2), f2b(o3));
    } else {
      *(float4*)((float*)outv + (size_t)row * 256 + colb) =
          make_float4(o0, o1, o2, o3);
    }
  }
}

// ---------------------------------------------------------------------------
// Gather attention: one block (256 thr) per (b,n) row.
// logits = content + sim - 0.25*geod + sum_i g_i*(-rAr/s_i^2 + cb_i*prior + mask_i*(-1e4))
// ---------------------------------------------------------------------------
__global__ __launch_bounds__(256) void k_attn(
    const u16* __restrict__ q, const u16* __restrict__ k,
    const u16* __restrict__ v, const float* __restrict__ S,
    const float* __restrict__ rel, const float* __restrict__ geod,
    const int* __restrict__ idx, const float* __restrict__ rowdat,
    u16* __restrict__ agg)
{
  int r = blockIdx.x;
  int b = r >> 14, n = r & (NB - 1);
  int t = threadIdx.x;
  __shared__ float qs[256];
  __shared__ float ss[64];
  __shared__ float cs[16];
  __shared__ float attb[16];
  __shared__ int nbr[16];

  qs[t] = b2f(q[(size_t)r * DD + t]) * 0.0625f;   // fold 1/sqrt(256)
  if (t < 64) ss[t] = S[(size_t)r * SDD + t];
  if (t < 16) nbr[t] = idx[n * 16 + t];
  __syncthreads();

  int w = t >> 6, lane = t & 63;
  for (int kk = w; kk < 16; kk += 4) {
    int g = (b << 14) + nbr[kk];
    ushort4 k4 = *(const ushort4*)(k + (size_t)g * DD + lane * 4);
    float4 q4 = *(const float4*)&qs[lane * 4];
    float p = q4.x * b2f(k4.x) + q4.y * b2f(k4.y) +
              q4.z * b2f(k4.z) + q4.w * b2f(k4.w);
    p += ss[lane] * S[(size_t)g * SDD + lane];   // sim contribution
    #pragma unroll
    for (int o = 32; o; o >>= 1) p += __shfl_down(p, o);
    if (lane == 0) cs[kk] = p;
  }
  __syncthreads();

  if (t < 16) {
    const float* rd = rowdat + (size_t)r * 8;
    float A00 = rd[0], A01 = rd[1], A11 = rd[2];
    float g0 = rd[3], g1 = rd[4], g2 = rd[5];
    float r0 = rel[(n * 16 + t) * 2];
    float r1 = rel[(n * 16 + t) * 2 + 1];
    float ge = geod[n * 16 + t];
    float rAr = A00 * r0 * r0 + 2.0f * A01 * r0 * r1 + A11 * r1 * r1;
    float prior = expf(-ge * ge * (1.0f / 2.25f));
    float lg = cs[t] - 0.25f * ge;
    { float s = 0.25f + 0.2f  * ge; float s2 = fmaxf(s * s, 1e-6f);
      lg += g0 * (-rAr / s2 + 0.7f * prior + (ge > 1.5f ? -10000.0f : 0.0f)); }
    { float s = 0.35f + 0.2f  * ge; float s2 = fmaxf(s * s, 1e-6f);
      lg += g1 * (-rAr / s2 + 0.5f * prior + (ge > 2.5f ? -10000.0f : 0.0f)); }
    { float s = 0.55f + 0.25f * ge; float s2 = fmaxf(s * s, 1e-6f);
      lg += g2 * (-rAr / s2 + 0.3f * prior + (ge > 4.0f ? -10000.0f : 0.0f)); }
    float m = lg;
    #pragma unroll
    for (int o = 1; o < 16; o <<= 1) m = fmaxf(m, __shfl_xor(m, o, 16));
    float e = expf(lg - m);
    float sme = e;
    #pragma unroll
    for (int o = 1; o < 16; o <<= 1) sme += __shfl_xor(sme, o, 16);
    attb[t] = e / sme;
  }
  __syncthreads();

  float acc = 0.0f;
  #pragma unroll
  for (int kk = 0; kk < 16; ++kk) {
    int g = (b << 14) + nbr[kk];
    acc += attb[kk] * b2f(v[(size_t)g * DD + t]);
  }
  agg[(size_t)r * DD + t] = f2b(acc);
}

// ---------------------------------------------------------------------------
// In-place LayerNorm over D=256, one wave per row (4 rows per block). f32 io.
// ---------------------------------------------------------------------------
__global__ __launch_bounds__(256) void k_ln(
    float* __restrict__ out, const float* __restrict__ lng, const float* __restrict__ lnb)
{
  int t = threadIdx.x;
  int w = t >> 6, lane = t & 63;
  int row = blockIdx.x * 4 + w;
  float4 h4 = *(const float4*)(out + (size_t)row * DD + lane * 4);
  float x0 = h4.x, x1 = h4.y, x2 = h4.z, x3 = h4.w;
  float s = x0 + x1 + x2 + x3;
  float sq = x0 * x0 + x1 * x1 + x2 * x2 + x3 * x3;
  #pragma unroll
  for (int o = 32; o; o >>= 1) { s += __shfl_xor(s, o); sq += __shfl_xor(sq, o); }
  float mu = s * (1.0f / 256.0f);
  float var = sq * (1.0f / 256.0f) - mu * mu;
  float rstd = rsqrtf(var + 1e-5f);
  int c = lane * 4;
  float4 g4 = *(const float4*)(lng + c);
  float4 b4 = *(const float4*)(lnb + c);
  *(float4*)(out + (size_t)row * DD + c) = make_float4(
      g4.x * (x0 - mu) * rstd + b4.x,
      g4.y * (x1 - mu) * rstd + b4.y,
      g4.z * (x2 - mu) * rstd + b4.z,
      g4.w * (x3 - mu) * rstd + b4.w);
}

// ---------------------------------------------------------------------------
// TV regularizer: sum |dA| along H and W into sums[0] (dy), sums[1] (dx).
// ---------------------------------------------------------------------------
__global__ __launch_bounds__(256) void k_tv(
    const float* __restrict__ an, float* __restrict__ sums)
{
  int gid = blockIdx.x * blockDim.x + threadIdx.x;
  int stride = gridDim.x * blockDim.x;
  float dy = 0.0f, dx = 0.0f;
  for (int e = gid; e < 4 * 127 * 128; e += stride) {   // dy: (B,127,128)
    int bb = e / 16256; int rem = e % 16256;
    int i = rem >> 7; int jj = rem & 127;
    int base = bb * 16384 + i * 128 + jj;
    dy += fabsf(an[base + 128] - an[base]);
  }
  for (int e = gid; e < 4 * 128 * 127; e += stride) {   // dx: (B,128,127)
    int bb = e / 16256; int rem = e % 16256;
    int i = rem / 127; int jj = rem % 127;
    int base = bb * 16384 + i * 128 + jj;
    dx += fabsf(an[base + 1] - an[base]);
  }
  #pragma unroll
  for (int o = 32; o; o >>= 1) { dy += __shfl_down(dy, o); dx += __shfl_down(dx, o); }
  if ((threadIdx.x & 63) == 0) {
    atomicAdd(&sums[0], dy);
    atomicAdd(&sums[1], dx);
  }
}

__global__ void k_reg(const float* __restrict__ sums, float* __restrict__ out)
{
  if (threadIdx.x == 0 && blockIdx.x == 0) {
    out[16777216] = 0.001f * (sums[0] + sums[1]) * (1.0f / 65024.0f);
  }
}

// ---------------------------------------------------------------------------
extern "C" void kernel_launch(void* const* d_in, const int* in_sizes, int n_in,
                              void* d_out, int out_size, void* d_ws, size_t ws_size,
                              hipStream_t stream)
{
  const float* z    = (const float*)d_in[0];
  const float* S    = (const float*)d_in[1];
  const float* rel  = (const float*)d_in[2];
  const float* geod = (const float*)d_in[3];
  const int*   idx  = (const int*)d_in[4];
  const float* Wq = (const float*)d_in[5];  const float* bq = (const float*)d_in[6];
  const float* Wk = (const float*)d_in[7];  const float* bk = (const float*)d_in[8];
  const float* Wv = (const float*)d_in[9];  const float* bv = (const float*)d_in[10];
  const float* Wo = (const float*)d_in[11]; const float* bo = (const float*)d_in[12];
  const float* lng = (const float*)d_in[13]; const float* lnb = (const float*)d_in[14];
  const float* Ws1 = (const float*)d_in[15]; const float* bs1 = (const float*)d_in[16];
  const float* Ws2 = (const float*)d_in[17]; const float* bs2 = (const float*)d_in[18];
  const float* Wzg = (const float*)d_in[19]; const float* bzg = (const float*)d_in[20];
  const float* Wph = (const float*)d_in[21]; const float* bph = (const float*)d_in[22];
  const float* Wsg = (const float*)d_in[23]; const float* bsg = (const float*)d_in[24];

  char* ws = (char*)d_ws;
  u16* qb = (u16*)ws;  ws += 33554432;          // 65536*256 bf16
  u16* kb = (u16*)ws;  ws += 33554432;
  u16* vb = (u16*)ws;  ws += 33554432;
  u16* ab = (u16*)ws;  ws += 33554432;
  float* rowdat = (float*)ws; ws += 2097152;    // 65536 * 8 f32
  float* anorm  = (float*)ws; ws += 262144;     // 65536 f32
  float* sums   = (float*)ws;                   // 2 f32

  float* outp = (float*)d_out;

  hipMemsetAsync(sums, 0, 8, stream);
  k_scalar<<<NROWS, 64, 0, stream>>>(z, S, Ws1, bs1, Ws2, bs2, Wzg, bzg,
                                     Wph, bph, Wsg, bsg, rowdat, anorm);
  k_gemm<0,1><<<dim3(1024, 4), 256, 0, stream>>>(z, Wq, bq, nullptr, qb);
  k_gemm<0,1><<<dim3(1024, 4), 256, 0, stream>>>(z, Wk, bk, nullptr, kb);
  k_gemm<0,1><<<dim3(1024, 4), 256, 0, stream>>>(z, Wv, bv, nullptr, vb);
  k_attn<<<NROWS, 256, 0, stream>>>(qb, kb, vb, S, rel, geod, idx, rowdat, ab);
  k_gemm<1,0><<<dim3(1024, 4), 256, 0, stream>>>(ab, Wo, bo, z, outp);  // h = z + agg@Wo + bo
  k_ln<<<NROWS / 4, 256, 0, stream>>>(outp, lng, lnb);
  k_tv<<<256, 256, 0, stream>>>(anorm, sums);
  k_reg<<<1, 64, 0, stream>>>(sums, outp);
}

// Round 3
// 604.823 us; speedup vs baseline: 1.6110x; 1.6110x over previous
//
#include <hip/hip_runtime.h>
#include <hip/hip_bf16.h>
#include <math.h>

// MGAT_24970939859571 — round 3: bf16-MFMA GEMMs (fused qkv + Wo), f32 io.
// B=4, N=16384 (128x128 grid), K=16 neighbors, D=256, SD=64.

typedef unsigned short u16;
typedef __attribute__((ext_vector_type(8))) short short8;
typedef __attribute__((ext_vector_type(4))) float f32x4;

#define NB 16384
#define NROWS 65536
#define DD 256
#define SDD 64

__device__ __forceinline__ float b2f(u16 u) {
  union { unsigned int i; float f; } c; c.i = ((unsigned int)u) << 16; return c.f;
}
__device__ __forceinline__ u16 f2b(float f) {
  union { float f; unsigned int i; } c; c.f = f;
  unsigned int i = c.i;
  return (u16)((i + 0x7FFFu + ((i >> 16) & 1u)) >> 16);  // RNE
}
__device__ __forceinline__ float gelu_exact(float x) {
  return 0.5f * x * (1.0f + erff(x * 0.70710678118654752f));
}
__device__ __forceinline__ void gll16(const u16* g, u16* l) {
  __builtin_amdgcn_global_load_lds(
      (const __attribute__((address_space(1))) void*)g,
      (__attribute__((address_space(3))) void*)l, 16, 0, 0);
}

// ---------------------------------------------------------------------------
// Prep: cast z to bf16 (grid-stride, float4).
// ---------------------------------------------------------------------------
__global__ __launch_bounds__(256) void k_prep_z(
    const float* __restrict__ z, u16* __restrict__ zb)
{
  int gid = blockIdx.x * 256 + threadIdx.x;
  int stride = gridDim.x * 256;
  for (int i = gid; i < 4194304; i += stride) {
    float4 v = ((const float4*)z)[i];
    ((ushort4*)zb)[i] = make_ushort4(f2b(v.x), f2b(v.y), f2b(v.z), f2b(v.w));
  }
}

// ---------------------------------------------------------------------------
// Prep: transposed bf16 weights. WqkvT[768][256]: WqkvT[j][k]=W_sel[k][j&255].
// WoT[256][256]: WoT[j][k]=Wo[k][j]. biasq[768] f32 concat.
// ---------------------------------------------------------------------------
__global__ __launch_bounds__(256) void k_prep_w(
    const float* __restrict__ Wq, const float* __restrict__ Wk,
    const float* __restrict__ Wv, const float* __restrict__ Wo,
    const float* __restrict__ bq, const float* __restrict__ bk,
    const float* __restrict__ bv,
    u16* __restrict__ WqkvT, u16* __restrict__ WoT, float* __restrict__ biasq)
{
  int gid = blockIdx.x * 256 + threadIdx.x;
  int stride = gridDim.x * 256;
  for (int e = gid; e < 196608; e += stride) {
    int j = e >> 8, kk = e & 255;
    int sel = j >> 8, jj = j & 255;
    const float* W = sel == 0 ? Wq : sel == 1 ? Wk : Wv;
    WqkvT[e] = f2b(W[kk * 256 + jj]);
  }
  for (int e = gid; e < 65536; e += stride) {
    int j = e >> 8, kk = e & 255;
    WoT[e] = f2b(Wo[kk * 256 + j]);
  }
  for (int e = gid; e < 768; e += stride)
    biasq[e] = e < 256 ? bq[e] : e < 512 ? bk[e - 256] : bv[e - 512];
}

// ---------------------------------------------------------------------------
// MFMA GEMM mainloop (shared shape): C[128x128] per block, BK=64, 4 waves,
// each wave 64x64 via 4x4 frags of mfma_f32_16x16x32_bf16.
// A [Mx256] bf16 row-major; BT [Nx256] bf16 row-major (B transposed).
// ---------------------------------------------------------------------------
#define MFMA_MAINLOOP(Aptr, BTptr)                                            \
  __shared__ u16 As[128 * 64];                                                \
  __shared__ u16 Bs[128 * 64];                                                \
  int t = threadIdx.x, wv = t >> 6, lane = t & 63;                            \
  int m0 = blockIdx.x * 128, j0 = blockIdx.y * 128;                           \
  int wm = (wv & 1) * 64, wn = (wv >> 1) * 64;                                \
  int quad = lane >> 4, l15 = lane & 15;                                      \
  int srow = lane >> 3, scol = (lane & 7) * 8;                                \
  f32x4 acc[4][4] = {};                                                       \
  for (int kc = 0; kc < 256; kc += 64) {                                      \
    if (kc) __syncthreads();                                                  \
    for (int it = 0; it < 4; ++it) {                                          \
      int c = it * 4 + wv;                                                    \
      gll16(Aptr + (size_t)(m0 + c * 8 + srow) * 256 + kc + scol,             \
            As + c * 512);                                                    \
      gll16(BTptr + (size_t)(j0 + c * 8 + srow) * 256 + kc + scol,            \
            Bs + c * 512);                                                    \
    }                                                                         \
    __syncthreads();                                                          \
    _Pragma("unroll")                                                         \
    for (int ks = 0; ks < 64; ks += 32) {                                     \
      short8 af[4], bfr[4];                                                   \
      _Pragma("unroll")                                                       \
      for (int mi = 0; mi < 4; ++mi)                                          \
        af[mi] = *(const short8*)&As[(wm + mi * 16 + l15) * 64 + ks + quad * 8]; \
      _Pragma("unroll")                                                       \
      for (int ni = 0; ni < 4; ++ni)                                          \
        bfr[ni] = *(const short8*)&Bs[(wn + ni * 16 + l15) * 64 + ks + quad * 8]; \
      _Pragma("unroll")                                                       \
      for (int mi = 0; mi < 4; ++mi)                                          \
        _Pragma("unroll")                                                     \
        for (int ni = 0; ni < 4; ++ni)                                        \
          acc[mi][ni] = __builtin_amdgcn_mfma_f32_16x16x32_bf16(              \
              af[mi], bfr[ni], acc[mi][ni], 0, 0, 0);                         \
    }                                                                         \
  }

// qkv GEMM: grid (512, 6); writes bf16 + bias into qb/kb/vb by column range.
__global__ __launch_bounds__(256) void k_mfma_qkv(
    const u16* __restrict__ A, const u16* __restrict__ BT,
    const float* __restrict__ biasq,
    u16* __restrict__ qb, u16* __restrict__ kb, u16* __restrict__ vb)
{
  MFMA_MAINLOOP(A, BT)
  u16* obuf = (j0 < 256) ? qb : (j0 < 512) ? kb : vb;
  int jb = j0 & 255;
  #pragma unroll
  for (int ni = 0; ni < 4; ++ni) {
    int gcol = j0 + wn + ni * 16 + l15;
    float bia = biasq[gcol];
    int colb = jb + wn + ni * 16 + l15;
    #pragma unroll
    for (int mi = 0; mi < 4; ++mi) {
      int grow = m0 + wm + mi * 16 + quad * 4;
      #pragma unroll
      for (int r = 0; r < 4; ++r)
        obuf[(size_t)(grow + r) * 256 + colb] = f2b(acc[mi][ni][r] + bia);
    }
  }
}

// Wo GEMM: grid (512, 2); out f32 = acc + bo + z (residual).
__global__ __launch_bounds__(256) void k_mfma_out(
    const u16* __restrict__ A, const u16* __restrict__ BT,
    const float* __restrict__ bo, const float* __restrict__ zres,
    float* __restrict__ outp)
{
  MFMA_MAINLOOP(A, BT)
  #pragma unroll
  for (int ni = 0; ni < 4; ++ni) {
    int gcol = j0 + wn + ni * 16 + l15;
    float bia = bo[gcol];
    #pragma unroll
    for (int mi = 0; mi < 4; ++mi) {
      int grow = m0 + wm + mi * 16 + quad * 4;
      #pragma unroll
      for (int r = 0; r < 4; ++r) {
        size_t off = (size_t)(grow + r) * 256 + gcol;
        outp[off] = acc[mi][ni][r] + bia + zres[off];
      }
    }
  }
}

// ---------------------------------------------------------------------------
// Per-row scalar path (unchanged except anorm folded into rowdat slot 6).
// ---------------------------------------------------------------------------
__global__ __launch_bounds__(64) void k_scalar(
    const float* __restrict__ z, const float* __restrict__ S,
    const float* __restrict__ Ws1, const float* __restrict__ bs1,
    const float* __restrict__ Ws2, const float* __restrict__ bs2,
    const float* __restrict__ Wzg, const float* __restrict__ bzg,
    const float* __restrict__ Wph, const float* __restrict__ bph,
    const float* __restrict__ Wsg, const float* __restrict__ bsg,
    float* __restrict__ rowdat)
{
  int r = blockIdx.x;
  int t = threadIdx.x;           // 0..63 (one wave)
  __shared__ float kin[32];
  __shared__ float h1s[16];
  __shared__ float abcs[8];

  float sv = S[(size_t)r * SDD + t];
  float s1 = sv, s2 = sv * sv;
  #pragma unroll
  for (int o = 32; o; o >>= 1) { s1 += __shfl_xor(s1, o); s2 += __shfl_xor(s2, o); }
  float m1 = s1 * (1.0f / 64.0f), m2 = s2 * (1.0f / 64.0f);

  int j = t & 15, grp = t >> 4;
  const float* zr = z + (size_t)r * DD + grp * 64;
  float acc = 0.0f;
  for (int i = 0; i < 64; ++i)
    acc += zr[i] * Wzg[(grp * 64 + i) * 16 + j];
  acc += __shfl_xor(acc, 16);
  acc += __shfl_xor(acc, 32);

  if (t < 16) {
    float h1 = m1 * Ws1[j] + m2 * Ws1[16 + j] + bs1[j];
    h1s[j] = gelu_exact(h1);
  }
  __syncthreads();
  if (t < 16) {
    float h2 = bs2[j];
    #pragma unroll
    for (int i = 0; i < 16; ++i) h2 += h1s[i] * Ws2[i * 16 + j];
    kin[j] = gelu_exact(h2);
    kin[16 + j] = gelu_exact(acc + bzg[j]);
  }
  __syncthreads();
  if (t < 6) {
    int c = t % 3;
    const float* Wp = (t < 3) ? Wph : Wsg;
    const float* bp = (t < 3) ? bph : bsg;
    float a = bp[c];
    #pragma unroll
    for (int i = 0; i < 32; ++i) a += kin[i] * Wp[i * 3 + c];
    abcs[t] = a;
  }
  __syncthreads();
  if (t == 0) {
    float La = expf(abcs[0]), Lb = abcs[1], Lc = expf(abcs[2]);
    float A00 = La * La, A01 = La * Lb, A11 = Lb * Lb + Lc * Lc;
    float g0 = abcs[3], g1 = abcs[4], g2 = abcs[5];
    float gm = fmaxf(g0, fmaxf(g1, g2));
    float e0 = expf(g0 - gm), e1 = expf(g1 - gm), e2 = expf(g2 - gm);
    float inv = 1.0f / (e0 + e1 + e2);
    float* rd = rowdat + (size_t)r * 8;
    rd[0] = A00; rd[1] = A01; rd[2] = A11;
    rd[3] = e0 * inv; rd[4] = e1 * inv; rd[5] = e2 * inv;
    rd[6] = sqrtf(A00 * A00 + 2.0f * A01 * A01 + A11 * A11);
  }
}

// ---------------------------------------------------------------------------
// Gather attention (unchanged from round 2).
// ---------------------------------------------------------------------------
__global__ __launch_bounds__(256) void k_attn(
    const u16* __restrict__ q, const u16* __restrict__ k,
    const u16* __restrict__ v, const float* __restrict__ S,
    const float* __restrict__ rel, const float* __restrict__ geod,
    const int* __restrict__ idx, const float* __restrict__ rowdat,
    u16* __restrict__ agg)
{
  int r = blockIdx.x;
  int b = r >> 14, n = r & (NB - 1);
  int t = threadIdx.x;
  __shared__ float qs[256];
  __shared__ float ss[64];
  __shared__ float cs[16];
  __shared__ float attb[16];
  __shared__ int nbr[16];

  qs[t] = b2f(q[(size_t)r * DD + t]) * 0.0625f;   // fold 1/sqrt(256)
  if (t < 64) ss[t] = S[(size_t)r * SDD + t];
  if (t < 16) nbr[t] = idx[n * 16 + t];
  __syncthreads();

  int w = t >> 6, lane = t & 63;
  for (int kk = w; kk < 16; kk += 4) {
    int g = (b << 14) + nbr[kk];
    ushort4 k4 = *(const ushort4*)(k + (size_t)g * DD + lane * 4);
    float4 q4 = *(const float4*)&qs[lane * 4];
    float p = q4.x * b2f(k4.x) + q4.y * b2f(k4.y) +
              q4.z * b2f(k4.z) + q4.w * b2f(k4.w);
    p += ss[lane] * S[(size_t)g * SDD + lane];
    #pragma unroll
    for (int o = 32; o; o >>= 1) p += __shfl_down(p, o);
    if (lane == 0) cs[kk] = p;
  }
  __syncthreads();

  if (t < 16) {
    const float* rd = rowdat + (size_t)r * 8;
    float A00 = rd[0], A01 = rd[1], A11 = rd[2];
    float g0 = rd[3], g1 = rd[4], g2 = rd[5];
    float r0 = rel[(n * 16 + t) * 2];
    float r1 = rel[(n * 16 + t) * 2 + 1];
    float ge = geod[n * 16 + t];
    float rAr = A00 * r0 * r0 + 2.0f * A01 * r0 * r1 + A11 * r1 * r1;
    float prior = expf(-ge * ge * (1.0f / 2.25f));
    float lg = cs[t] - 0.25f * ge;
    { float s = 0.25f + 0.2f  * ge; float s2 = fmaxf(s * s, 1e-6f);
      lg += g0 * (-rAr / s2 + 0.7f * prior + (ge > 1.5f ? -10000.0f : 0.0f)); }
    { float s = 0.35f + 0.2f  * ge; float s2 = fmaxf(s * s, 1e-6f);
      lg += g1 * (-rAr / s2 + 0.5f * prior + (ge > 2.5f ? -10000.0f : 0.0f)); }
    { float s = 0.55f + 0.25f * ge; float s2 = fmaxf(s * s, 1e-6f);
      lg += g2 * (-rAr / s2 + 0.3f * prior + (ge > 4.0f ? -10000.0f : 0.0f)); }
    float m = lg;
    #pragma unroll
    for (int o = 1; o < 16; o <<= 1) m = fmaxf(m, __shfl_xor(m, o, 16));
    float e = expf(lg - m);
    float sme = e;
    #pragma unroll
    for (int o = 1; o < 16; o <<= 1) sme += __shfl_xor(sme, o, 16);
    attb[t] = e / sme;
  }
  __syncthreads();

  float acc = 0.0f;
  #pragma unroll
  for (int kk = 0; kk < 16; ++kk) {
    int g = (b << 14) + nbr[kk];
    acc += attb[kk] * b2f(v[(size_t)g * DD + t]);
  }
  agg[(size_t)r * DD + t] = f2b(acc);
}

// ---------------------------------------------------------------------------
// In-place LayerNorm over D=256, one wave per row (4 rows per block). f32 io.
// ---------------------------------------------------------------------------
__global__ __launch_bounds__(256) void k_ln(
    float* __restrict__ out, const float* __restrict__ lng, const float* __restrict__ lnb)
{
  int t = threadIdx.x;
  int w = t >> 6, lane = t & 63;
  int row = blockIdx.x * 4 + w;
  float4 h4 = *(const float4*)(out + (size_t)row * DD + lane * 4);
  float x0 = h4.x, x1 = h4.y, x2 = h4.z, x3 = h4.w;
  float s = x0 + x1 + x2 + x3;
  float sq = x0 * x0 + x1 * x1 + x2 * x2 + x3 * x3;
  #pragma unroll
  for (int o = 32; o; o >>= 1) { s += __shfl_xor(s, o); sq += __shfl_xor(sq, o); }
  float mu = s * (1.0f / 256.0f);
  float var = sq * (1.0f / 256.0f) - mu * mu;
  float rstd = rsqrtf(var + 1e-5f);
  int c = lane * 4;
  float4 g4 = *(const float4*)(lng + c);
  float4 b4 = *(const float4*)(lnb + c);
  *(float4*)(out + (size_t)row * DD + c) = make_float4(
      g4.x * (x0 - mu) * rstd + b4.x,
      g4.y * (x1 - mu) * rstd + b4.y,
      g4.z * (x2 - mu) * rstd + b4.z,
      g4.w * (x3 - mu) * rstd + b4.w);
}

// ---------------------------------------------------------------------------
// TV regularizer over anorm (stored at rowdat[r*8+6]).
// ---------------------------------------------------------------------------
__global__ __launch_bounds__(256) void k_tv(
    const float* __restrict__ rowdat, float* __restrict__ sums)
{
  int gid = blockIdx.x * blockDim.x + threadIdx.x;
  int stride = gridDim.x * blockDim.x;
  float dy = 0.0f, dx = 0.0f;
  for (int e = gid; e < 4 * 127 * 128; e += stride) {   // dy: (B,127,128)
    int bb = e / 16256; int rem = e % 16256;
    int i = rem >> 7; int jj = rem & 127;
    int base = bb * 16384 + i * 128 + jj;
    dy += fabsf(rowdat[(size_t)(base + 128) * 8 + 6] - rowdat[(size_t)base * 8 + 6]);
  }
  for (int e = gid; e < 4 * 128 * 127; e += stride) {   // dx: (B,128,127)
    int bb = e / 16256; int rem = e % 16256;
    int i = rem / 127; int jj = rem % 127;
    int base = bb * 16384 + i * 128 + jj;
    dx += fabsf(rowdat[(size_t)(base + 1) * 8 + 6] - rowdat[(size_t)base * 8 + 6]);
  }
  #pragma unroll
  for (int o = 32; o; o >>= 1) { dy += __shfl_down(dy, o); dx += __shfl_down(dx, o); }
  if ((threadIdx.x & 63) == 0) {
    atomicAdd(&sums[0], dy);
    atomicAdd(&sums[1], dx);
  }
}

__global__ void k_reg(const float* __restrict__ sums, float* __restrict__ out)
{
  if (threadIdx.x == 0 && blockIdx.x == 0) {
    out[16777216] = 0.001f * (sums[0] + sums[1]) * (1.0f / 65024.0f);
  }
}

// ---------------------------------------------------------------------------
extern "C" void kernel_launch(void* const* d_in, const int* in_sizes, int n_in,
                              void* d_out, int out_size, void* d_ws, size_t ws_size,
                              hipStream_t stream)
{
  const float* z    = (const float*)d_in[0];
  const float* S    = (const float*)d_in[1];
  const float* rel  = (const float*)d_in[2];
  const float* geod = (const float*)d_in[3];
  const int*   idx  = (const int*)d_in[4];
  const float* Wq = (const float*)d_in[5];  const float* bq = (const float*)d_in[6];
  const float* Wk = (const float*)d_in[7];  const float* bk = (const float*)d_in[8];
  const float* Wv = (const float*)d_in[9];  const float* bv = (const float*)d_in[10];
  const float* Wo = (const float*)d_in[11]; const float* bo = (const float*)d_in[12];
  const float* lng = (const float*)d_in[13]; const float* lnb = (const float*)d_in[14];
  const float* Ws1 = (const float*)d_in[15]; const float* bs1 = (const float*)d_in[16];
  const float* Ws2 = (const float*)d_in[17]; const float* bs2 = (const float*)d_in[18];
  const float* Wzg = (const float*)d_in[19]; const float* bzg = (const float*)d_in[20];
  const float* Wph = (const float*)d_in[21]; const float* bph = (const float*)d_in[22];
  const float* Wsg = (const float*)d_in[23]; const float* bsg = (const float*)d_in[24];

  char* ws = (char*)d_ws;
  u16* zb = (u16*)ws;  ws += 33554432;          // z bf16; ALIASED as agg (ab) after qkv GEMM
  u16* qb = (u16*)ws;  ws += 33554432;
  u16* kb = (u16*)ws;  ws += 33554432;
  u16* vb = (u16*)ws;  ws += 33554432;
  u16* WqkvT = (u16*)ws; ws += 393216;          // 768*256 bf16
  u16* WoT   = (u16*)ws; ws += 131072;          // 256*256 bf16
  float* biasq = (float*)ws; ws += 3072;        // 768 f32
  float* rowdat = (float*)ws; ws += 2097152;    // 65536*8 f32 (slot6 = anorm)
  float* sums   = (float*)ws;                   // 2 f32
  u16* ab = zb;                                 // alias: zb dead after qkv GEMM

  float* outp = (float*)d_out;

  hipMemsetAsync(sums, 0, 8, stream);
  k_prep_z<<<4096, 256, 0, stream>>>(z, zb);
  k_prep_w<<<256, 256, 0, stream>>>(Wq, Wk, Wv, Wo, bq, bk, bv, WqkvT, WoT, biasq);
  k_scalar<<<NROWS, 64, 0, stream>>>(z, S, Ws1, bs1, Ws2, bs2, Wzg, bzg,
                                     Wph, bph, Wsg, bsg, rowdat);
  k_mfma_qkv<<<dim3(512, 6), 256, 0, stream>>>(zb, WqkvT, biasq, qb, kb, vb);
  k_attn<<<NROWS, 256, 0, stream>>>(qb, kb, vb, S, rel, geod, idx, rowdat, ab);
  k_mfma_out<<<dim3(512, 2), 256, 0, stream>>>(ab, WoT, bo, z, outp);
  k_ln<<<NROWS / 4, 256, 0, stream>>>(outp, lng, lnb);
  k_tv<<<256, 256, 0, stream>>>(rowdat, sums);
  k_reg<<<1, 64, 0, stream>>>(sums, outp);
}

// Round 4
// 496.000 us; speedup vs baseline: 1.9645x; 1.2194x over previous
//
#include <hip/hip_runtime.h>
#include <hip/hip_bf16.h>
#include <math.h>

// MGAT_24970939859571 — round 4: wave-per-row attention, fused z-cast,
// bf16-MFMA GEMMs (fused qkv + Wo). f32 io.
// B=4, N=16384 (128x128 grid), K=16 neighbors, D=256, SD=64.

typedef unsigned short u16;
typedef __attribute__((ext_vector_type(8))) short short8;
typedef __attribute__((ext_vector_type(4))) float f32x4;

#define NB 16384
#define NROWS 65536
#define DD 256
#define SDD 64

__device__ __forceinline__ float b2f(u16 u) {
  union { unsigned int i; float f; } c; c.i = ((unsigned int)u) << 16; return c.f;
}
__device__ __forceinline__ float blo(unsigned int u) {
  union { unsigned int i; float f; } c; c.i = u << 16; return c.f;
}
__device__ __forceinline__ float bhi(unsigned int u) {
  union { unsigned int i; float f; } c; c.i = u & 0xFFFF0000u; return c.f;
}
__device__ __forceinline__ u16 f2b(float f) {
  union { float f; unsigned int i; } c; c.f = f;
  unsigned int i = c.i;
  return (u16)((i + 0x7FFFu + ((i >> 16) & 1u)) >> 16);  // RNE
}
__device__ __forceinline__ float gelu_exact(float x) {
  return 0.5f * x * (1.0f + erff(x * 0.70710678118654752f));
}
__device__ __forceinline__ void gll16(const u16* g, u16* l) {
  __builtin_amdgcn_global_load_lds(
      (const __attribute__((address_space(1))) void*)g,
      (__attribute__((address_space(3))) void*)l, 16, 0, 0);
}

// ---------------------------------------------------------------------------
// Prep: transposed bf16 weights + concat bias.
// ---------------------------------------------------------------------------
__global__ __launch_bounds__(256) void k_prep_w(
    const float* __restrict__ Wq, const float* __restrict__ Wk,
    const float* __restrict__ Wv, const float* __restrict__ Wo,
    const float* __restrict__ bq, const float* __restrict__ bk,
    const float* __restrict__ bv,
    u16* __restrict__ WqkvT, u16* __restrict__ WoT, float* __restrict__ biasq)
{
  int gid = blockIdx.x * 256 + threadIdx.x;
  int stride = gridDim.x * 256;
  for (int e = gid; e < 196608; e += stride) {
    int j = e >> 8, kk = e & 255;
    int sel = j >> 8, jj = j & 255;
    const float* W = sel == 0 ? Wq : sel == 1 ? Wk : Wv;
    WqkvT[e] = f2b(W[kk * 256 + jj]);
  }
  for (int e = gid; e < 65536; e += stride) {
    int j = e >> 8, kk = e & 255;
    WoT[e] = f2b(Wo[kk * 256 + j]);
  }
  for (int e = gid; e < 768; e += stride)
    biasq[e] = e < 256 ? bq[e] : e < 512 ? bk[e - 256] : bv[e - 512];
}

// ---------------------------------------------------------------------------
// MFMA GEMM mainloop: C[128x128]/block, BK=64, 4 waves, 4x4 16x16x32 frags.
// ---------------------------------------------------------------------------
#define MFMA_MAINLOOP(Aptr, BTptr)                                            \
  __shared__ u16 As[128 * 64];                                                \
  __shared__ u16 Bs[128 * 64];                                                \
  int t = threadIdx.x, wv = t >> 6, lane = t & 63;                            \
  int m0 = blockIdx.x * 128, j0 = blockIdx.y * 128;                           \
  int wm = (wv & 1) * 64, wn = (wv >> 1) * 64;                                \
  int quad = lane >> 4, l15 = lane & 15;                                      \
  int srow = lane >> 3, scol = (lane & 7) * 8;                                \
  f32x4 acc[4][4] = {};                                                       \
  for (int kc = 0; kc < 256; kc += 64) {                                      \
    if (kc) __syncthreads();                                                  \
    for (int it = 0; it < 4; ++it) {                                          \
      int c = it * 4 + wv;                                                    \
      gll16(Aptr + (size_t)(m0 + c * 8 + srow) * 256 + kc + scol,             \
            As + c * 512);                                                    \
      gll16(BTptr + (size_t)(j0 + c * 8 + srow) * 256 + kc + scol,            \
            Bs + c * 512);                                                    \
    }                                                                         \
    __syncthreads();                                                          \
    _Pragma("unroll")                                                         \
    for (int ks = 0; ks < 64; ks += 32) {                                     \
      short8 af[4], bfr[4];                                                   \
      _Pragma("unroll")                                                       \
      for (int mi = 0; mi < 4; ++mi)                                          \
        af[mi] = *(const short8*)&As[(wm + mi * 16 + l15) * 64 + ks + quad * 8]; \
      _Pragma("unroll")                                                       \
      for (int ni = 0; ni < 4; ++ni)                                          \
        bfr[ni] = *(const short8*)&Bs[(wn + ni * 16 + l15) * 64 + ks + quad * 8]; \
      _Pragma("unroll")                                                       \
      for (int mi = 0; mi < 4; ++mi)                                          \
        _Pragma("unroll")                                                     \
        for (int ni = 0; ni < 4; ++ni)                                        \
          acc[mi][ni] = __builtin_amdgcn_mfma_f32_16x16x32_bf16(              \
              af[mi], bfr[ni], acc[mi][ni], 0, 0, 0);                         \
    }                                                                         \
  }

__global__ __launch_bounds__(256) void k_mfma_qkv(
    const u16* __restrict__ A, const u16* __restrict__ BT,
    const float* __restrict__ biasq,
    u16* __restrict__ qb, u16* __restrict__ kb, u16* __restrict__ vb)
{
  MFMA_MAINLOOP(A, BT)
  u16* obuf = (j0 < 256) ? qb : (j0 < 512) ? kb : vb;
  int jb = j0 & 255;
  #pragma unroll
  for (int ni = 0; ni < 4; ++ni) {
    int gcol = j0 + wn + ni * 16 + l15;
    float bia = biasq[gcol];
    int colb = jb + wn + ni * 16 + l15;
    #pragma unroll
    for (int mi = 0; mi < 4; ++mi) {
      int grow = m0 + wm + mi * 16 + quad * 4;
      #pragma unroll
      for (int r = 0; r < 4; ++r)
        obuf[(size_t)(grow + r) * 256 + colb] = f2b(acc[mi][ni][r] + bia);
    }
  }
}

__global__ __launch_bounds__(256) void k_mfma_out(
    const u16* __restrict__ A, const u16* __restrict__ BT,
    const float* __restrict__ bo, const float* __restrict__ zres,
    float* __restrict__ outp)
{
  MFMA_MAINLOOP(A, BT)
  #pragma unroll
  for (int ni = 0; ni < 4; ++ni) {
    int gcol = j0 + wn + ni * 16 + l15;
    float bia = bo[gcol];
    #pragma unroll
    for (int mi = 0; mi < 4; ++mi) {
      int grow = m0 + wm + mi * 16 + quad * 4;
      #pragma unroll
      for (int r = 0; r < 4; ++r) {
        size_t off = (size_t)(grow + r) * 256 + gcol;
        outp[off] = acc[mi][ni][r] + bia + zres[off];
      }
    }
  }
}

// ---------------------------------------------------------------------------
// Per-row scalar path + fused z->bf16 cast. 4 rows per 256-thr block.
// ---------------------------------------------------------------------------
__global__ __launch_bounds__(256) void k_scalar(
    const float* __restrict__ z, const float* __restrict__ S,
    const float* __restrict__ Ws1, const float* __restrict__ bs1,
    const float* __restrict__ Ws2, const float* __restrict__ bs2,
    const float* __restrict__ Wzg, const float* __restrict__ bzg,
    const float* __restrict__ Wph, const float* __restrict__ bph,
    const float* __restrict__ Wsg, const float* __restrict__ bsg,
    u16* __restrict__ zb, float* __restrict__ rowdat)
{
  int w = threadIdx.x >> 6, t = threadIdx.x & 63;
  int r = blockIdx.x * 4 + w;
  __shared__ float kin[4][32];
  __shared__ float h1s[4][16];
  __shared__ float abcs[4][8];

  // fused cast: z row -> zb
  float4 zv = *(const float4*)(z + (size_t)r * DD + t * 4);
  *(ushort4*)(zb + (size_t)r * DD + t * 4) =
      make_ushort4(f2b(zv.x), f2b(zv.y), f2b(zv.z), f2b(zv.w));

  float sv = S[(size_t)r * SDD + t];
  float s1 = sv, s2 = sv * sv;
  #pragma unroll
  for (int o = 32; o; o >>= 1) { s1 += __shfl_xor(s1, o); s2 += __shfl_xor(s2, o); }
  float m1 = s1 * (1.0f / 64.0f), m2 = s2 * (1.0f / 64.0f);

  int j = t & 15, grp = t >> 4;
  const float* zr = z + (size_t)r * DD + grp * 64;
  float acc = 0.0f;
  for (int i = 0; i < 64; ++i)
    acc += zr[i] * Wzg[(grp * 64 + i) * 16 + j];
  acc += __shfl_xor(acc, 16);
  acc += __shfl_xor(acc, 32);

  if (t < 16) {
    float h1 = m1 * Ws1[j] + m2 * Ws1[16 + j] + bs1[j];
    h1s[w][j] = gelu_exact(h1);
  }
  __syncthreads();
  if (t < 16) {
    float h2 = bs2[j];
    #pragma unroll
    for (int i = 0; i < 16; ++i) h2 += h1s[w][i] * Ws2[i * 16 + j];
    kin[w][j] = gelu_exact(h2);
    kin[w][16 + j] = gelu_exact(acc + bzg[j]);
  }
  __syncthreads();
  if (t < 6) {
    int c = t % 3;
    const float* Wp = (t < 3) ? Wph : Wsg;
    const float* bp = (t < 3) ? bph : bsg;
    float a = bp[c];
    #pragma unroll
    for (int i = 0; i < 32; ++i) a += kin[w][i] * Wp[i * 3 + c];
    abcs[w][t] = a;
  }
  __syncthreads();
  if (t == 0) {
    float La = expf(abcs[w][0]), Lb = abcs[w][1], Lc = expf(abcs[w][2]);
    float A00 = La * La, A01 = La * Lb, A11 = Lb * Lb + Lc * Lc;
    float g0 = abcs[w][3], g1 = abcs[w][4], g2 = abcs[w][5];
    float gm = fmaxf(g0, fmaxf(g1, g2));
    float e0 = expf(g0 - gm), e1 = expf(g1 - gm), e2 = expf(g2 - gm);
    float inv = 1.0f / (e0 + e1 + e2);
    float* rd = rowdat + (size_t)r * 8;
    rd[0] = A00; rd[1] = A01; rd[2] = A11;
    rd[3] = e0 * inv; rd[4] = e1 * inv; rd[5] = e2 * inv;
    rd[6] = sqrtf(A00 * A00 + 2.0f * A01 * A01 + A11 * A11);
  }
}

// ---------------------------------------------------------------------------
// Gather attention — ONE WAVE PER ROW. 4 rows per 256-thr block.
// Lane layout: g = lane>>2 (neighbor 0..15), sub = lane&3.
// ---------------------------------------------------------------------------
__global__ __launch_bounds__(256) void k_attn(
    const u16* __restrict__ q, const u16* __restrict__ k,
    const u16* __restrict__ v, const float* __restrict__ S,
    const float* __restrict__ rel, const float* __restrict__ geod,
    const int* __restrict__ idx, const float* __restrict__ rowdat,
    u16* __restrict__ agg)
{
  __shared__ float qs[4][256];
  __shared__ float ss[4][64];
  int w = threadIdx.x >> 6, lane = threadIdx.x & 63;
  int r = blockIdx.x * 4 + w;
  int b = r >> 14, n = r & (NB - 1);

  // stage q (scaled by 1/sqrt(256)) and S row into LDS
  {
    ushort4 q4 = *(const ushort4*)(q + (size_t)r * DD + lane * 4);
    qs[w][lane * 4 + 0] = b2f(q4.x) * 0.0625f;
    qs[w][lane * 4 + 1] = b2f(q4.y) * 0.0625f;
    qs[w][lane * 4 + 2] = b2f(q4.z) * 0.0625f;
    qs[w][lane * 4 + 3] = b2f(q4.w) * 0.0625f;
    ss[w][lane] = S[(size_t)r * SDD + lane];
  }
  __syncthreads();

  int g = lane >> 2, sub = lane & 3;
  int nbr = idx[n * 16 + g];
  size_t gidx = ((size_t)b << 14) + nbr;

  // content (q.kN) + sim (S.S_n), each 4-lane group handles one neighbor
  const u16* krow = k + gidx * DD;
  float p = 0.0f;
  #pragma unroll
  for (int c = 0; c < 8; ++c) {
    int e = (c * 4 + sub) * 8;
    uint2 ka = *(const uint2*)(krow + e);
    uint2 kb2 = *(const uint2*)(krow + e + 4);
    const float* qp = &qs[w][e];
    p += blo(ka.x) * qp[0] + bhi(ka.x) * qp[1]
       + blo(ka.y) * qp[2] + bhi(ka.y) * qp[3]
       + blo(kb2.x) * qp[4] + bhi(kb2.x) * qp[5]
       + blo(kb2.y) * qp[6] + bhi(kb2.y) * qp[7];
  }
  const float* Srow = S + gidx * SDD;
  #pragma unroll
  for (int c = 0; c < 4; ++c) {
    int e = sub * 16 + c * 4;
    float4 s4 = *(const float4*)(Srow + e);
    const float* sp = &ss[w][e];
    p += s4.x * sp[0] + s4.y * sp[1] + s4.z * sp[2] + s4.w * sp[3];
  }
  p += __shfl_xor(p, 1);
  p += __shfl_xor(p, 2);     // replicated across the 4 lanes of the group

  // logits (computed redundantly by all 4 lanes of each group)
  const float* rd = rowdat + (size_t)r * 8;
  float A00 = rd[0], A01 = rd[1], A11 = rd[2];
  float g0 = rd[3], g1 = rd[4], g2 = rd[5];
  float r0 = rel[(n * 16 + g) * 2];
  float r1 = rel[(n * 16 + g) * 2 + 1];
  float ge = geod[n * 16 + g];
  float rAr = A00 * r0 * r0 + 2.0f * A01 * r0 * r1 + A11 * r1 * r1;
  float prior = expf(-ge * ge * (1.0f / 2.25f));
  float lg = p - 0.25f * ge;
  { float s = 0.25f + 0.2f  * ge; float s2 = fmaxf(s * s, 1e-6f);
    lg += g0 * (-rAr / s2 + 0.7f * prior + (ge > 1.5f ? -10000.0f : 0.0f)); }
  { float s = 0.35f + 0.2f  * ge; float s2 = fmaxf(s * s, 1e-6f);
    lg += g1 * (-rAr / s2 + 0.5f * prior + (ge > 2.5f ? -10000.0f : 0.0f)); }
  { float s = 0.55f + 0.25f * ge; float s2 = fmaxf(s * s, 1e-6f);
    lg += g2 * (-rAr / s2 + 0.3f * prior + (ge > 4.0f ? -10000.0f : 0.0f)); }

  // softmax over 16 groups (values replicated x4 -> butterfly over 4,8,16,32)
  float m = lg;
  m = fmaxf(m, __shfl_xor(m, 4));
  m = fmaxf(m, __shfl_xor(m, 8));
  m = fmaxf(m, __shfl_xor(m, 16));
  m = fmaxf(m, __shfl_xor(m, 32));
  float e = expf(lg - m);
  float sm = e;
  sm += __shfl_xor(sm, 4);
  sm += __shfl_xor(sm, 8);
  sm += __shfl_xor(sm, 16);
  sm += __shfl_xor(sm, 32);
  float att = e / sm;

  // v aggregation: lane owns output cols lane*4..lane*4+3
  float a0 = 0.f, a1 = 0.f, a2 = 0.f, a3 = 0.f;
  size_t bbase = (size_t)b << 14;
  #pragma unroll
  for (int kk = 0; kk < 16; ++kk) {
    float akk = __shfl(att, kk * 4);
    int nb2 = __shfl(nbr, kk * 4);
    const u16* vrow = v + (bbase + nb2) * DD;
    uint2 v4 = *(const uint2*)(vrow + lane * 4);
    a0 += akk * blo(v4.x);
    a1 += akk * bhi(v4.x);
    a2 += akk * blo(v4.y);
    a3 += akk * bhi(v4.y);
  }
  *(ushort4*)(agg + (size_t)r * DD + lane * 4) =
      make_ushort4(f2b(a0), f2b(a1), f2b(a2), f2b(a3));
}

// ---------------------------------------------------------------------------
// In-place LayerNorm over D=256, one wave per row (4 rows per block). f32 io.
// ---------------------------------------------------------------------------
__global__ __launch_bounds__(256) void k_ln(
    float* __restrict__ out, const float* __restrict__ lng, const float* __restrict__ lnb)
{
  int t = threadIdx.x;
  int w = t >> 6, lane = t & 63;
  int row = blockIdx.x * 4 + w;
  float4 h4 = *(const float4*)(out + (size_t)row * DD + lane * 4);
  float x0 = h4.x, x1 = h4.y, x2 = h4.z, x3 = h4.w;
  float s = x0 + x1 + x2 + x3;
  float sq = x0 * x0 + x1 * x1 + x2 * x2 + x3 * x3;
  #pragma unroll
  for (int o = 32; o; o >>= 1) { s += __shfl_xor(s, o); sq += __shfl_xor(sq, o); }
  float mu = s * (1.0f / 256.0f);
  float var = sq * (1.0f / 256.0f) - mu * mu;
  float rstd = rsqrtf(var + 1e-5f);
  int c = lane * 4;
  float4 g4 = *(const float4*)(lng + c);
  float4 b4 = *(const float4*)(lnb + c);
  *(float4*)(out + (size_t)row * DD + c) = make_float4(
      g4.x * (x0 - mu) * rstd + b4.x,
      g4.y * (x1 - mu) * rstd + b4.y,
      g4.z * (x2 - mu) * rstd + b4.z,
      g4.w * (x3 - mu) * rstd + b4.w);
}

// ---------------------------------------------------------------------------
// TV regularizer over anorm (stored at rowdat[r*8+6]).
// ---------------------------------------------------------------------------
__global__ __launch_bounds__(256) void k_tv(
    const float* __restrict__ rowdat, float* __restrict__ sums)
{
  int gid = blockIdx.x * blockDim.x + threadIdx.x;
  int stride = gridDim.x * blockDim.x;
  float dy = 0.0f, dx = 0.0f;
  for (int e = gid; e < 4 * 127 * 128; e += stride) {
    int bb = e / 16256; int rem = e % 16256;
    int i = rem >> 7; int jj = rem & 127;
    int base = bb * 16384 + i * 128 + jj;
    dy += fabsf(rowdat[(size_t)(base + 128) * 8 + 6] - rowdat[(size_t)base * 8 + 6]);
  }
  for (int e = gid; e < 4 * 128 * 127; e += stride) {
    int bb = e / 16256; int rem = e % 16256;
    int i = rem / 127; int jj = rem % 127;
    int base = bb * 16384 + i * 128 + jj;
    dx += fabsf(rowdat[(size_t)(base + 1) * 8 + 6] - rowdat[(size_t)base * 8 + 6]);
  }
  #pragma unroll
  for (int o = 32; o; o >>= 1) { dy += __shfl_down(dy, o); dx += __shfl_down(dx, o); }
  if ((threadIdx.x & 63) == 0) {
    atomicAdd(&sums[0], dy);
    atomicAdd(&sums[1], dx);
  }
}

__global__ void k_reg(const float* __restrict__ sums, float* __restrict__ out)
{
  if (threadIdx.x == 0 && blockIdx.x == 0) {
    out[16777216] = 0.001f * (sums[0] + sums[1]) * (1.0f / 65024.0f);
  }
}

// ---------------------------------------------------------------------------
extern "C" void kernel_launch(void* const* d_in, const int* in_sizes, int n_in,
                              void* d_out, int out_size, void* d_ws, size_t ws_size,
                              hipStream_t stream)
{
  const float* z    = (const float*)d_in[0];
  const float* S    = (const float*)d_in[1];
  const float* rel  = (const float*)d_in[2];
  const float* geod = (const float*)d_in[3];
  const int*   idx  = (const int*)d_in[4];
  const float* Wq = (const float*)d_in[5];  const float* bq = (const float*)d_in[6];
  const float* Wk = (const float*)d_in[7];  const float* bk = (const float*)d_in[8];
  const float* Wv = (const float*)d_in[9];  const float* bv = (const float*)d_in[10];
  const float* Wo = (const float*)d_in[11]; const float* bo = (const float*)d_in[12];
  const float* lng = (const float*)d_in[13]; const float* lnb = (const float*)d_in[14];
  const float* Ws1 = (const float*)d_in[15]; const float* bs1 = (const float*)d_in[16];
  const float* Ws2 = (const float*)d_in[17]; const float* bs2 = (const float*)d_in[18];
  const float* Wzg = (const float*)d_in[19]; const float* bzg = (const float*)d_in[20];
  const float* Wph = (const float*)d_in[21]; const float* bph = (const float*)d_in[22];
  const float* Wsg = (const float*)d_in[23]; const float* bsg = (const float*)d_in[24];

  char* ws = (char*)d_ws;
  u16* zb = (u16*)ws;  ws += 33554432;          // z bf16; ALIASED as agg after qkv GEMM
  u16* qb = (u16*)ws;  ws += 33554432;
  u16* kb = (u16*)ws;  ws += 33554432;
  u16* vb = (u16*)ws;  ws += 33554432;
  u16* WqkvT = (u16*)ws; ws += 393216;
  u16* WoT   = (u16*)ws; ws += 131072;
  float* biasq = (float*)ws; ws += 3072;
  float* rowdat = (float*)ws; ws += 2097152;    // 65536*8 f32 (slot6 = anorm)
  float* sums   = (float*)ws;
  u16* ab = zb;                                 // alias: zb dead after qkv GEMM

  float* outp = (float*)d_out;

  hipMemsetAsync(sums, 0, 8, stream);
  k_prep_w<<<256, 256, 0, stream>>>(Wq, Wk, Wv, Wo, bq, bk, bv, WqkvT, WoT, biasq);
  k_scalar<<<NROWS / 4, 256, 0, stream>>>(z, S, Ws1, bs1, Ws2, bs2, Wzg, bzg,
                                          Wph, bph, Wsg, bsg, zb, rowdat);
  k_mfma_qkv<<<dim3(512, 6), 256, 0, stream>>>(zb, WqkvT, biasq, qb, kb, vb);
  k_attn<<<NROWS / 4, 256, 0, stream>>>(qb, kb, vb, S, rel, geod, idx, rowdat, ab);
  k_mfma_out<<<dim3(512, 2), 256, 0, stream>>>(ab, WoT, bo, z, outp);
  k_ln<<<NROWS / 4, 256, 0, stream>>>(outp, lng, lnb);
  k_tv<<<256, 256, 0, stream>>>(rowdat, sums);
  k_reg<<<1, 64, 0, stream>>>(sums, outp);
}

// Round 5
// 459.318 us; speedup vs baseline: 2.1214x; 1.0799x over previous
//
#include <hip/hip_runtime.h>
#include <hip/hip_bf16.h>
#include <math.h>

// MGAT_24970939859571 — round 5: LDS-staged k_scalar matvec, LN fused into
// Wo-GEMM epilogue (128x256 blocks), wave-per-row attention, MFMA GEMMs.
// B=4, N=16384 (128x128 grid), K=16 neighbors, D=256, SD=64. f32 io.

typedef unsigned short u16;
typedef __attribute__((ext_vector_type(8))) short short8;
typedef __attribute__((ext_vector_type(4))) float f32x4;

#define NB 16384
#define NROWS 65536
#define DD 256
#define SDD 64

__device__ __forceinline__ float b2f(u16 u) {
  union { unsigned int i; float f; } c; c.i = ((unsigned int)u) << 16; return c.f;
}
__device__ __forceinline__ float blo(unsigned int u) {
  union { unsigned int i; float f; } c; c.i = u << 16; return c.f;
}
__device__ __forceinline__ float bhi(unsigned int u) {
  union { unsigned int i; float f; } c; c.i = u & 0xFFFF0000u; return c.f;
}
__device__ __forceinline__ u16 f2b(float f) {
  union { float f; unsigned int i; } c; c.f = f;
  unsigned int i = c.i;
  return (u16)((i + 0x7FFFu + ((i >> 16) & 1u)) >> 16);  // RNE
}
__device__ __forceinline__ float gelu_exact(float x) {
  return 0.5f * x * (1.0f + erff(x * 0.70710678118654752f));
}
__device__ __forceinline__ void gll16(const u16* g, u16* l) {
  __builtin_amdgcn_global_load_lds(
      (const __attribute__((address_space(1))) void*)g,
      (__attribute__((address_space(3))) void*)l, 16, 0, 0);
}

// ---------------------------------------------------------------------------
// Prep: transposed bf16 weights + concat bias.
// ---------------------------------------------------------------------------
__global__ __launch_bounds__(256) void k_prep_w(
    const float* __restrict__ Wq, const float* __restrict__ Wk,
    const float* __restrict__ Wv, const float* __restrict__ Wo,
    const float* __restrict__ bq, const float* __restrict__ bk,
    const float* __restrict__ bv,
    u16* __restrict__ WqkvT, u16* __restrict__ WoT, float* __restrict__ biasq)
{
  int gid = blockIdx.x * 256 + threadIdx.x;
  int stride = gridDim.x * 256;
  for (int e = gid; e < 196608; e += stride) {
    int j = e >> 8, kk = e & 255;
    int sel = j >> 8, jj = j & 255;
    const float* W = sel == 0 ? Wq : sel == 1 ? Wk : Wv;
    WqkvT[e] = f2b(W[kk * 256 + jj]);
  }
  for (int e = gid; e < 65536; e += stride) {
    int j = e >> 8, kk = e & 255;
    WoT[e] = f2b(Wo[kk * 256 + j]);
  }
  for (int e = gid; e < 768; e += stride)
    biasq[e] = e < 256 ? bq[e] : e < 512 ? bk[e - 256] : bv[e - 512];
}

// ---------------------------------------------------------------------------
// qkv MFMA GEMM: C[128x128]/block, BK=64, 4 waves, 4x4 16x16x32 frags.
// ---------------------------------------------------------------------------
__global__ __launch_bounds__(256) void k_mfma_qkv(
    const u16* __restrict__ A, const u16* __restrict__ BT,
    const float* __restrict__ biasq,
    u16* __restrict__ qb, u16* __restrict__ kb, u16* __restrict__ vb)
{
  __shared__ u16 As[128 * 64];
  __shared__ u16 Bs[128 * 64];
  int t = threadIdx.x, wv = t >> 6, lane = t & 63;
  int m0 = blockIdx.x * 128, j0 = blockIdx.y * 128;
  int wm = (wv & 1) * 64, wn = (wv >> 1) * 64;
  int quad = lane >> 4, l15 = lane & 15;
  int srow = lane >> 3, scol = (lane & 7) * 8;
  f32x4 acc[4][4] = {};
  for (int kc = 0; kc < 256; kc += 64) {
    if (kc) __syncthreads();
    for (int it = 0; it < 4; ++it) {
      int c = it * 4 + wv;
      gll16(A + (size_t)(m0 + c * 8 + srow) * 256 + kc + scol, As + c * 512);
      gll16(BT + (size_t)(j0 + c * 8 + srow) * 256 + kc + scol, Bs + c * 512);
    }
    __syncthreads();
    #pragma unroll
    for (int ks = 0; ks < 64; ks += 32) {
      short8 af[4], bfr[4];
      #pragma unroll
      for (int mi = 0; mi < 4; ++mi)
        af[mi] = *(const short8*)&As[(wm + mi * 16 + l15) * 64 + ks + quad * 8];
      #pragma unroll
      for (int ni = 0; ni < 4; ++ni)
        bfr[ni] = *(const short8*)&Bs[(wn + ni * 16 + l15) * 64 + ks + quad * 8];
      #pragma unroll
      for (int mi = 0; mi < 4; ++mi)
        #pragma unroll
        for (int ni = 0; ni < 4; ++ni)
          acc[mi][ni] = __builtin_amdgcn_mfma_f32_16x16x32_bf16(
              af[mi], bfr[ni], acc[mi][ni], 0, 0, 0);
    }
  }
  u16* obuf = (j0 < 256) ? qb : (j0 < 512) ? kb : vb;
  int jb = j0 & 255;
  #pragma unroll
  for (int ni = 0; ni < 4; ++ni) {
    int gcol = j0 + wn + ni * 16 + l15;
    float bia = biasq[gcol];
    int colb = jb + wn + ni * 16 + l15;
    #pragma unroll
    for (int mi = 0; mi < 4; ++mi) {
      int grow = m0 + wm + mi * 16 + quad * 4;
      #pragma unroll
      for (int r = 0; r < 4; ++r)
        obuf[(size_t)(grow + r) * 256 + colb] = f2b(acc[mi][ni][r] + bia);
    }
  }
}

// ---------------------------------------------------------------------------
// Wo GEMM + residual + LayerNorm fused. C[128x256]/block (grid 512), 4 waves,
// each wave 32 rows x 256 cols = 2x16 frags. Row LN via 16-lane shfl reduce.
// ---------------------------------------------------------------------------
__global__ __launch_bounds__(256) void k_mfma_out_ln(
    const u16* __restrict__ A, const u16* __restrict__ BT,
    const float* __restrict__ bo, const float* __restrict__ zres,
    const float* __restrict__ lng, const float* __restrict__ lnb,
    float* __restrict__ outp)
{
  __shared__ u16 As[128 * 64];
  __shared__ u16 Bs[256 * 64];
  int t = threadIdx.x, wv = t >> 6, lane = t & 63;
  int m0 = blockIdx.x * 128;
  int wm = wv * 32;
  int quad = lane >> 4, l15 = lane & 15;
  int srow = lane >> 3, scol = (lane & 7) * 8;
  f32x4 acc[2][16] = {};
  for (int kc = 0; kc < 256; kc += 64) {
    if (kc) __syncthreads();
    #pragma unroll
    for (int it = 0; it < 4; ++it) {
      int c = it * 4 + wv;
      gll16(A + (size_t)(m0 + c * 8 + srow) * 256 + kc + scol, As + c * 512);
    }
    #pragma unroll
    for (int it = 0; it < 8; ++it) {
      int c = it * 4 + wv;
      gll16(BT + (size_t)(c * 8 + srow) * 256 + kc + scol, Bs + c * 512);
    }
    __syncthreads();
    #pragma unroll
    for (int ks = 0; ks < 64; ks += 32) {
      short8 af[2], bfr[16];
      #pragma unroll
      for (int mi = 0; mi < 2; ++mi)
        af[mi] = *(const short8*)&As[(wm + mi * 16 + l15) * 64 + ks + quad * 8];
      #pragma unroll
      for (int ni = 0; ni < 16; ++ni)
        bfr[ni] = *(const short8*)&Bs[(ni * 16 + l15) * 64 + ks + quad * 8];
      #pragma unroll
      for (int mi = 0; mi < 2; ++mi)
        #pragma unroll
        for (int ni = 0; ni < 16; ++ni)
          acc[mi][ni] = __builtin_amdgcn_mfma_f32_16x16x32_bf16(
              af[mi], bfr[ni], acc[mi][ni], 0, 0, 0);
    }
  }
  // epilogue: +bo +z residual, then row LayerNorm, write f32
  float lg_[16], lb_[16], bo_[16];
  #pragma unroll
  for (int ni = 0; ni < 16; ++ni) {
    int col = ni * 16 + l15;
    lg_[ni] = lng[col]; lb_[ni] = lnb[col]; bo_[ni] = bo[col];
  }
  #pragma unroll
  for (int mi = 0; mi < 2; ++mi) {
    #pragma unroll
    for (int rr = 0; rr < 4; ++rr) {
      int row = m0 + wm + mi * 16 + quad * 4 + rr;
      float x[16];
      float s = 0.0f, sq = 0.0f;
      #pragma unroll
      for (int ni = 0; ni < 16; ++ni) {
        int col = ni * 16 + l15;
        float v = acc[mi][ni][rr] + bo_[ni] + zres[(size_t)row * 256 + col];
        x[ni] = v; s += v; sq += v * v;
      }
      #pragma unroll
      for (int o = 1; o < 16; o <<= 1) {
        s += __shfl_xor(s, o);
        sq += __shfl_xor(sq, o);
      }
      float mu = s * (1.0f / 256.0f);
      float var = sq * (1.0f / 256.0f) - mu * mu;
      float rstd = rsqrtf(var + 1e-5f);
      #pragma unroll
      for (int ni = 0; ni < 16; ++ni) {
        int col = ni * 16 + l15;
        outp[(size_t)row * 256 + col] = lg_[ni] * (x[ni] - mu) * rstd + lb_[ni];
      }
    }
  }
}

// ---------------------------------------------------------------------------
// Per-row scalar path + fused z->bf16 cast. 4 rows per 256-thr block.
// z row + Wzg staged in LDS; matvec reads LDS only.
// ---------------------------------------------------------------------------
__global__ __launch_bounds__(256) void k_scalar(
    const float* __restrict__ z, const float* __restrict__ S,
    const float* __restrict__ Ws1, const float* __restrict__ bs1,
    const float* __restrict__ Ws2, const float* __restrict__ bs2,
    const float* __restrict__ Wzg, const float* __restrict__ bzg,
    const float* __restrict__ Wph, const float* __restrict__ bph,
    const float* __restrict__ Wsg, const float* __restrict__ bsg,
    u16* __restrict__ zb, float* __restrict__ rowdat)
{
  __shared__ float wzg[256][17];   // stride 17: Wzg[i][j]
  __shared__ float zrow[4][256];
  __shared__ float kin[4][32];
  __shared__ float h1s[4][16];
  __shared__ float abcs[4][8];

  int tid = threadIdx.x;
  // stage Wzg (4096 f32) once per block
  for (int e = tid; e < 4096; e += 256)
    wzg[e >> 4][e & 15] = Wzg[e];

  int w = tid >> 6, t = tid & 63;
  int r = blockIdx.x * 4 + w;

  // load z row (float4/lane), fused bf16-cast store + LDS stage
  float4 zv = *(const float4*)(z + (size_t)r * DD + t * 4);
  *(ushort4*)(zb + (size_t)r * DD + t * 4) =
      make_ushort4(f2b(zv.x), f2b(zv.y), f2b(zv.z), f2b(zv.w));
  *(float4*)&zrow[w][t * 4] = zv;

  // S row stats (no barrier needed — wave-local)
  float sv = S[(size_t)r * SDD + t];
  float s1 = sv, s2 = sv * sv;
  #pragma unroll
  for (int o = 32; o; o >>= 1) { s1 += __shfl_xor(s1, o); s2 += __shfl_xor(s2, o); }
  float m1 = s1 * (1.0f / 64.0f), m2 = s2 * (1.0f / 64.0f);

  __syncthreads();   // wzg + zrow staged

  // z_emb matvec from LDS: lane j=t&15, grp covers i in [grp*64, grp*64+64)
  int j = t & 15, grp = t >> 4;
  float acc = 0.0f;
  #pragma unroll
  for (int step = 0; step < 16; ++step) {
    int i = grp * 64 + step * 4;
    float4 z4 = *(const float4*)&zrow[w][i];
    acc += z4.x * wzg[i][j] + z4.y * wzg[i + 1][j]
         + z4.z * wzg[i + 2][j] + z4.w * wzg[i + 3][j];
  }
  acc += __shfl_xor(acc, 16);
  acc += __shfl_xor(acc, 32);

  if (t < 16) {
    float h1 = m1 * Ws1[j] + m2 * Ws1[16 + j] + bs1[j];
    h1s[w][j] = gelu_exact(h1);
  }
  __syncthreads();
  if (t < 16) {
    float h2 = bs2[j];
    #pragma unroll
    for (int i = 0; i < 16; ++i) h2 += h1s[w][i] * Ws2[i * 16 + j];
    kin[w][j] = gelu_exact(h2);
    kin[w][16 + j] = gelu_exact(acc + bzg[j]);
  }
  __syncthreads();
  if (t < 6) {
    int c = t % 3;
    const float* Wp = (t < 3) ? Wph : Wsg;
    const float* bp = (t < 3) ? bph : bsg;
    float a = bp[c];
    #pragma unroll
    for (int i = 0; i < 32; ++i) a += kin[w][i] * Wp[i * 3 + c];
    abcs[w][t] = a;
  }
  __syncthreads();
  if (t == 0) {
    float La = expf(abcs[w][0]), Lb = abcs[w][1], Lc = expf(abcs[w][2]);
    float A00 = La * La, A01 = La * Lb, A11 = Lb * Lb + Lc * Lc;
    float g0 = abcs[w][3], g1 = abcs[w][4], g2 = abcs[w][5];
    float gm = fmaxf(g0, fmaxf(g1, g2));
    float e0 = expf(g0 - gm), e1 = expf(g1 - gm), e2 = expf(g2 - gm);
    float inv = 1.0f / (e0 + e1 + e2);
    float* rd = rowdat + (size_t)r * 8;
    rd[0] = A00; rd[1] = A01; rd[2] = A11;
    rd[3] = e0 * inv; rd[4] = e1 * inv; rd[5] = e2 * inv;
    rd[6] = sqrtf(A00 * A00 + 2.0f * A01 * A01 + A11 * A11);
  }
}

// ---------------------------------------------------------------------------
// Gather attention — ONE WAVE PER ROW. 4 rows per 256-thr block.
// ---------------------------------------------------------------------------
__global__ __launch_bounds__(256) void k_attn(
    const u16* __restrict__ q, const u16* __restrict__ k,
    const u16* __restrict__ v, const float* __restrict__ S,
    const float* __restrict__ rel, const float* __restrict__ geod,
    const int* __restrict__ idx, const float* __restrict__ rowdat,
    u16* __restrict__ agg)
{
  __shared__ float qs[4][256];
  __shared__ float ss[4][64];
  int w = threadIdx.x >> 6, lane = threadIdx.x & 63;
  int r = blockIdx.x * 4 + w;
  int b = r >> 14, n = r & (NB - 1);

  {
    ushort4 q4 = *(const ushort4*)(q + (size_t)r * DD + lane * 4);
    qs[w][lane * 4 + 0] = b2f(q4.x) * 0.0625f;
    qs[w][lane * 4 + 1] = b2f(q4.y) * 0.0625f;
    qs[w][lane * 4 + 2] = b2f(q4.z) * 0.0625f;
    qs[w][lane * 4 + 3] = b2f(q4.w) * 0.0625f;
    ss[w][lane] = S[(size_t)r * SDD + lane];
  }
  __syncthreads();

  int g = lane >> 2, sub = lane & 3;
  int nbr = idx[n * 16 + g];
  size_t gidx = ((size_t)b << 14) + nbr;

  const u16* krow = k + gidx * DD;
  float p = 0.0f;
  #pragma unroll
  for (int c = 0; c < 8; ++c) {
    int e = (c * 4 + sub) * 8;
    uint2 ka = *(const uint2*)(krow + e);
    uint2 kb2 = *(const uint2*)(krow + e + 4);
    const float* qp = &qs[w][e];
    p += blo(ka.x) * qp[0] + bhi(ka.x) * qp[1]
       + blo(ka.y) * qp[2] + bhi(ka.y) * qp[3]
       + blo(kb2.x) * qp[4] + bhi(kb2.x) * qp[5]
       + blo(kb2.y) * qp[6] + bhi(kb2.y) * qp[7];
  }
  const float* Srow = S + gidx * SDD;
  #pragma unroll
  for (int c = 0; c < 4; ++c) {
    int e = sub * 16 + c * 4;
    float4 s4 = *(const float4*)(Srow + e);
    const float* sp = &ss[w][e];
    p += s4.x * sp[0] + s4.y * sp[1] + s4.z * sp[2] + s4.w * sp[3];
  }
  p += __shfl_xor(p, 1);
  p += __shfl_xor(p, 2);

  const float* rd = rowdat + (size_t)r * 8;
  float A00 = rd[0], A01 = rd[1], A11 = rd[2];
  float g0 = rd[3], g1 = rd[4], g2 = rd[5];
  float r0 = rel[(n * 16 + g) * 2];
  float r1 = rel[(n * 16 + g) * 2 + 1];
  float ge = geod[n * 16 + g];
  float rAr = A00 * r0 * r0 + 2.0f * A01 * r0 * r1 + A11 * r1 * r1;
  float prior = expf(-ge * ge * (1.0f / 2.25f));
  float lg = p - 0.25f * ge;
  { float s = 0.25f + 0.2f  * ge; float s2 = fmaxf(s * s, 1e-6f);
    lg += g0 * (-rAr / s2 + 0.7f * prior + (ge > 1.5f ? -10000.0f : 0.0f)); }
  { float s = 0.35f + 0.2f  * ge; float s2 = fmaxf(s * s, 1e-6f);
    lg += g1 * (-rAr / s2 + 0.5f * prior + (ge > 2.5f ? -10000.0f : 0.0f)); }
  { float s = 0.55f + 0.25f * ge; float s2 = fmaxf(s * s, 1e-6f);
    lg += g2 * (-rAr / s2 + 0.3f * prior + (ge > 4.0f ? -10000.0f : 0.0f)); }

  float m = lg;
  m = fmaxf(m, __shfl_xor(m, 4));
  m = fmaxf(m, __shfl_xor(m, 8));
  m = fmaxf(m, __shfl_xor(m, 16));
  m = fmaxf(m, __shfl_xor(m, 32));
  float e = expf(lg - m);
  float sm = e;
  sm += __shfl_xor(sm, 4);
  sm += __shfl_xor(sm, 8);
  sm += __shfl_xor(sm, 16);
  sm += __shfl_xor(sm, 32);
  float att = e / sm;

  float a0 = 0.f, a1 = 0.f, a2 = 0.f, a3 = 0.f;
  size_t bbase = (size_t)b << 14;
  #pragma unroll
  for (int kk = 0; kk < 16; ++kk) {
    float akk = __shfl(att, kk * 4);
    int nb2 = __shfl(nbr, kk * 4);
    const u16* vrow = v + (bbase + nb2) * DD;
    uint2 v4 = *(const uint2*)(vrow + lane * 4);
    a0 += akk * blo(v4.x);
    a1 += akk * bhi(v4.x);
    a2 += akk * blo(v4.y);
    a3 += akk * bhi(v4.y);
  }
  *(ushort4*)(agg + (size_t)r * DD + lane * 4) =
      make_ushort4(f2b(a0), f2b(a1), f2b(a2), f2b(a3));
}

// ---------------------------------------------------------------------------
// TV regularizer over anorm (stored at rowdat[r*8+6]).
// ---------------------------------------------------------------------------
__global__ __launch_bounds__(256) void k_tv(
    const float* __restrict__ rowdat, float* __restrict__ sums)
{
  int gid = blockIdx.x * blockDim.x + threadIdx.x;
  int stride = gridDim.x * blockDim.x;
  float dy = 0.0f, dx = 0.0f;
  for (int e = gid; e < 4 * 127 * 128; e += stride) {
    int bb = e / 16256; int rem = e % 16256;
    int i = rem >> 7; int jj = rem & 127;
    int base = bb * 16384 + i * 128 + jj;
    dy += fabsf(rowdat[(size_t)(base + 128) * 8 + 6] - rowdat[(size_t)base * 8 + 6]);
  }
  for (int e = gid; e < 4 * 128 * 127; e += stride) {
    int bb = e / 16256; int rem = e % 16256;
    int i = rem / 127; int jj = rem % 127;
    int base = bb * 16384 + i * 128 + jj;
    dx += fabsf(rowdat[(size_t)(base + 1) * 8 + 6] - rowdat[(size_t)base * 8 + 6]);
  }
  #pragma unroll
  for (int o = 32; o; o >>= 1) { dy += __shfl_down(dy, o); dx += __shfl_down(dx, o); }
  if ((threadIdx.x & 63) == 0) {
    atomicAdd(&sums[0], dy);
    atomicAdd(&sums[1], dx);
  }
}

__global__ void k_reg(const float* __restrict__ sums, float* __restrict__ out)
{
  if (threadIdx.x == 0 && blockIdx.x == 0) {
    out[16777216] = 0.001f * (sums[0] + sums[1]) * (1.0f / 65024.0f);
  }
}

// ---------------------------------------------------------------------------
extern "C" void kernel_launch(void* const* d_in, const int* in_sizes, int n_in,
                              void* d_out, int out_size, void* d_ws, size_t ws_size,
                              hipStream_t stream)
{
  const float* z    = (const float*)d_in[0];
  const float* S    = (const float*)d_in[1];
  const float* rel  = (const float*)d_in[2];
  const float* geod = (const float*)d_in[3];
  const int*   idx  = (const int*)d_in[4];
  const float* Wq = (const float*)d_in[5];  const float* bq = (const float*)d_in[6];
  const float* Wk = (const float*)d_in[7];  const float* bk = (const float*)d_in[8];
  const float* Wv = (const float*)d_in[9];  const float* bv = (const float*)d_in[10];
  const float* Wo = (const float*)d_in[11]; const float* bo = (const float*)d_in[12];
  const float* lng = (const float*)d_in[13]; const float* lnb = (const float*)d_in[14];
  const float* Ws1 = (const float*)d_in[15]; const float* bs1 = (const float*)d_in[16];
  const float* Ws2 = (const float*)d_in[17]; const float* bs2 = (const float*)d_in[18];
  const float* Wzg = (const float*)d_in[19]; const float* bzg = (const float*)d_in[20];
  const float* Wph = (const float*)d_in[21]; const float* bph = (const float*)d_in[22];
  const float* Wsg = (const float*)d_in[23]; const float* bsg = (const float*)d_in[24];

  char* ws = (char*)d_ws;
  u16* zb = (u16*)ws;  ws += 33554432;          // z bf16; ALIASED as agg after qkv GEMM
  u16* qb = (u16*)ws;  ws += 33554432;
  u16* kb = (u16*)ws;  ws += 33554432;
  u16* vb = (u16*)ws;  ws += 33554432;
  u16* WqkvT = (u16*)ws; ws += 393216;
  u16* WoT   = (u16*)ws; ws += 131072;
  float* biasq = (float*)ws; ws += 3072;
  float* rowdat = (float*)ws; ws += 2097152;    // 65536*8 f32 (slot6 = anorm)
  float* sums   = (float*)ws;
  u16* ab = zb;                                 // alias: zb dead after qkv GEMM

  float* outp = (float*)d_out;

  hipMemsetAsync(sums, 0, 8, stream);
  k_prep_w<<<256, 256, 0, stream>>>(Wq, Wk, Wv, Wo, bq, bk, bv, WqkvT, WoT, biasq);
  k_scalar<<<NROWS / 4, 256, 0, stream>>>(z, S, Ws1, bs1, Ws2, bs2, Wzg, bzg,
                                          Wph, bph, Wsg, bsg, zb, rowdat);
  k_mfma_qkv<<<dim3(512, 6), 256, 0, stream>>>(zb, WqkvT, biasq, qb, kb, vb);
  k_attn<<<NROWS / 4, 256, 0, stream>>>(qb, kb, vb, S, rel, geod, idx, rowdat, ab);
  k_mfma_out_ln<<<512, 256, 0, stream>>>(ab, WoT, bo, z, lng, lnb, outp);
  k_tv<<<256, 256, 0, stream>>>(rowdat, sums);
  k_reg<<<1, 64, 0, stream>>>(sums, outp);
}

// Round 6
// 419.287 us; speedup vs baseline: 2.3239x; 1.0955x over previous
//
#include <hip/hip_runtime.h>
#include <hip/hip_bf16.h>
#include <math.h>

// MGAT_24970939859571 — round 6: z_emb folded into qkv MFMA GEMM (7th tile),
// k_scalar split into streaming k_pre + tiny k_post. LN fused in Wo GEMM.
// B=4, N=16384 (128x128 grid), K=16 neighbors, D=256, SD=64. f32 io.

typedef unsigned short u16;
typedef __attribute__((ext_vector_type(8))) short short8;
typedef __attribute__((ext_vector_type(4))) float f32x4;

#define NB 16384
#define NROWS 65536
#define DD 256
#define SDD 64

__device__ __forceinline__ float b2f(u16 u) {
  union { unsigned int i; float f; } c; c.i = ((unsigned int)u) << 16; return c.f;
}
__device__ __forceinline__ float blo(unsigned int u) {
  union { unsigned int i; float f; } c; c.i = u << 16; return c.f;
}
__device__ __forceinline__ float bhi(unsigned int u) {
  union { unsigned int i; float f; } c; c.i = u & 0xFFFF0000u; return c.f;
}
__device__ __forceinline__ u16 f2b(float f) {
  union { float f; unsigned int i; } c; c.f = f;
  unsigned int i = c.i;
  return (u16)((i + 0x7FFFu + ((i >> 16) & 1u)) >> 16);  // RNE
}
__device__ __forceinline__ float gelu_exact(float x) {
  return 0.5f * x * (1.0f + erff(x * 0.70710678118654752f));
}
__device__ __forceinline__ void gll16(const u16* g, u16* l) {
  __builtin_amdgcn_global_load_lds(
      (const __attribute__((address_space(1))) void*)g,
      (__attribute__((address_space(3))) void*)l, 16, 0, 0);
}

// ---------------------------------------------------------------------------
// Prep: WqkvT[896][256] bf16 = [WqT; WkT; WvT; WzgT; zeros], WoT, biasq[784].
// ---------------------------------------------------------------------------
__global__ __launch_bounds__(256) void k_prep_w(
    const float* __restrict__ Wq, const float* __restrict__ Wk,
    const float* __restrict__ Wv, const float* __restrict__ Wo,
    const float* __restrict__ Wzg,
    const float* __restrict__ bq, const float* __restrict__ bk,
    const float* __restrict__ bv, const float* __restrict__ bzg,
    u16* __restrict__ WqkvT, u16* __restrict__ WoT, float* __restrict__ biasq)
{
  int gid = blockIdx.x * 256 + threadIdx.x;
  int stride = gridDim.x * 256;
  for (int e = gid; e < 229376; e += stride) {   // 896*256
    int j = e >> 8, kk = e & 255;
    float v;
    if (j < 256)      v = Wq[kk * 256 + j];
    else if (j < 512) v = Wk[kk * 256 + (j - 256)];
    else if (j < 768) v = Wv[kk * 256 + (j - 512)];
    else if (j < 784) v = Wzg[kk * 16 + (j - 768)];
    else              v = 0.0f;
    WqkvT[e] = f2b(v);
  }
  for (int e = gid; e < 65536; e += stride) {
    int j = e >> 8, kk = e & 255;
    WoT[e] = f2b(Wo[kk * 256 + j]);
  }
  for (int e = gid; e < 784; e += stride)
    biasq[e] = e < 256 ? bq[e] : e < 512 ? bk[e - 256]
             : e < 768 ? bv[e - 512] : bzg[e - 768];
}

// ---------------------------------------------------------------------------
// k_pre: z->bf16 cast + S row stats (m1,m2 -> rowdat slots 0,1). Streaming.
// 4 rows per 256-thr block, wave-local only.
// ---------------------------------------------------------------------------
__global__ __launch_bounds__(256) void k_pre(
    const float* __restrict__ z, const float* __restrict__ S,
    u16* __restrict__ zb, float* __restrict__ rowdat)
{
  int w = threadIdx.x >> 6, t = threadIdx.x & 63;
  int r = blockIdx.x * 4 + w;
  float4 zv = *(const float4*)(z + (size_t)r * DD + t * 4);
  *(ushort4*)(zb + (size_t)r * DD + t * 4) =
      make_ushort4(f2b(zv.x), f2b(zv.y), f2b(zv.z), f2b(zv.w));
  float sv = S[(size_t)r * SDD + t];
  float s1 = sv, s2 = sv * sv;
  #pragma unroll
  for (int o = 32; o; o >>= 1) { s1 += __shfl_xor(s1, o); s2 += __shfl_xor(s2, o); }
  if (t == 0) {
    rowdat[(size_t)r * 8 + 0] = s1 * (1.0f / 64.0f);
    rowdat[(size_t)r * 8 + 1] = s2 * (1.0f / 64.0f);
  }
}

// ---------------------------------------------------------------------------
// qkv (+z_emb) MFMA GEMM: C[128x128]/block, grid (512,7), BK=64, 4 waves.
// j-tiles 0..5 -> q/k/v bf16; tile 6 -> ze[.][0..15] f32 with gelu(.+bzg).
// ---------------------------------------------------------------------------
__global__ __launch_bounds__(256) void k_mfma_qkv(
    const u16* __restrict__ A, const u16* __restrict__ BT,
    const float* __restrict__ biasq,
    u16* __restrict__ qb, u16* __restrict__ kb, u16* __restrict__ vb,
    float* __restrict__ ze)
{
  __shared__ u16 As[128 * 64];
  __shared__ u16 Bs[128 * 64];
  int t = threadIdx.x, wv = t >> 6, lane = t & 63;
  int m0 = blockIdx.x * 128, j0 = blockIdx.y * 128;
  int wm = (wv & 1) * 64, wn = (wv >> 1) * 64;
  int quad = lane >> 4, l15 = lane & 15;
  int srow = lane >> 3, scol = (lane & 7) * 8;
  f32x4 acc[4][4] = {};
  for (int kc = 0; kc < 256; kc += 64) {
    if (kc) __syncthreads();
    for (int it = 0; it < 4; ++it) {
      int c = it * 4 + wv;
      gll16(A + (size_t)(m0 + c * 8 + srow) * 256 + kc + scol, As + c * 512);
      gll16(BT + (size_t)(j0 + c * 8 + srow) * 256 + kc + scol, Bs + c * 512);
    }
    __syncthreads();
    #pragma unroll
    for (int ks = 0; ks < 64; ks += 32) {
      short8 af[4], bfr[4];
      #pragma unroll
      for (int mi = 0; mi < 4; ++mi)
        af[mi] = *(const short8*)&As[(wm + mi * 16 + l15) * 64 + ks + quad * 8];
      #pragma unroll
      for (int ni = 0; ni < 4; ++ni)
        bfr[ni] = *(const short8*)&Bs[(wn + ni * 16 + l15) * 64 + ks + quad * 8];
      #pragma unroll
      for (int mi = 0; mi < 4; ++mi)
        #pragma unroll
        for (int ni = 0; ni < 4; ++ni)
          acc[mi][ni] = __builtin_amdgcn_mfma_f32_16x16x32_bf16(
              af[mi], bfr[ni], acc[mi][ni], 0, 0, 0);
    }
  }
  if (j0 < 768) {
    u16* obuf = (j0 < 256) ? qb : (j0 < 512) ? kb : vb;
    int jb = j0 & 255;
    #pragma unroll
    for (int ni = 0; ni < 4; ++ni) {
      int gcol = j0 + wn + ni * 16 + l15;
      float bia = biasq[gcol];
      int colb = jb + wn + ni * 16 + l15;
      #pragma unroll
      for (int mi = 0; mi < 4; ++mi) {
        int grow = m0 + wm + mi * 16 + quad * 4;
        #pragma unroll
        for (int r = 0; r < 4; ++r)
          obuf[(size_t)(grow + r) * 256 + colb] = f2b(acc[mi][ni][r] + bia);
      }
    }
  } else if (wn == 0) {
    // z_emb tile: only cols 0..15 valid (ni=0, wn=0)
    float bia = biasq[768 + l15];
    #pragma unroll
    for (int mi = 0; mi < 4; ++mi) {
      int grow = m0 + wm + mi * 16 + quad * 4;
      #pragma unroll
      for (int r = 0; r < 4; ++r)
        ze[(size_t)(grow + r) * 16 + l15] = gelu_exact(acc[mi][0][r] + bia);
    }
  }
}

// ---------------------------------------------------------------------------
// k_post: per-row tiny MLP. 16 rows per 256-thr block; lane j = tid&15.
// Reads m1/m2 (rowdat 0,1) + ze; writes rowdat slots 0-6.
// ---------------------------------------------------------------------------
__global__ __launch_bounds__(256) void k_post(
    const float* __restrict__ ze,
    const float* __restrict__ Ws1, const float* __restrict__ bs1,
    const float* __restrict__ Ws2, const float* __restrict__ bs2,
    const float* __restrict__ Wph, const float* __restrict__ bph,
    const float* __restrict__ Wsg, const float* __restrict__ bsg,
    float* __restrict__ rowdat)
{
  __shared__ float h1s[16][17];
  __shared__ float kin[16][33];
  __shared__ float abcs[16][8];
  int rloc = threadIdx.x >> 4, j = threadIdx.x & 15;
  int r = blockIdx.x * 16 + rloc;
  float m1 = rowdat[(size_t)r * 8 + 0];
  float m2 = rowdat[(size_t)r * 8 + 1];
  h1s[rloc][j] = gelu_exact(m1 * Ws1[j] + m2 * Ws1[16 + j] + bs1[j]);
  __syncthreads();
  float h2 = bs2[j];
  #pragma unroll
  for (int i = 0; i < 16; ++i) h2 += h1s[rloc][i] * Ws2[i * 16 + j];
  kin[rloc][j] = gelu_exact(h2);
  kin[rloc][16 + j] = ze[(size_t)r * 16 + j];   // already gelu'd
  __syncthreads();
  if (j < 6) {
    int c = j % 3;
    const float* Wp = (j < 3) ? Wph : Wsg;
    const float* bp = (j < 3) ? bph : bsg;
    float a = bp[c];
    #pragma unroll
    for (int i = 0; i < 32; ++i) a += kin[rloc][i] * Wp[i * 3 + c];
    abcs[rloc][j] = a;
  }
  __syncthreads();
  if (j == 0) {
    float La = expf(abcs[rloc][0]), Lb = abcs[rloc][1], Lc = expf(abcs[rloc][2]);
    float A00 = La * La, A01 = La * Lb, A11 = Lb * Lb + Lc * Lc;
    float g0 = abcs[rloc][3], g1 = abcs[rloc][4], g2 = abcs[rloc][5];
    float gm = fmaxf(g0, fmaxf(g1, g2));
    float e0 = expf(g0 - gm), e1 = expf(g1 - gm), e2 = expf(g2 - gm);
    float inv = 1.0f / (e0 + e1 + e2);
    float* rd = rowdat + (size_t)r * 8;
    rd[0] = A00; rd[1] = A01; rd[2] = A11;
    rd[3] = e0 * inv; rd[4] = e1 * inv; rd[5] = e2 * inv;
    rd[6] = sqrtf(A00 * A00 + 2.0f * A01 * A01 + A11 * A11);
  }
}

// ---------------------------------------------------------------------------
// Gather attention — ONE WAVE PER ROW. 4 rows per 256-thr block.
// ---------------------------------------------------------------------------
__global__ __launch_bounds__(256) void k_attn(
    const u16* __restrict__ q, const u16* __restrict__ k,
    const u16* __restrict__ v, const float* __restrict__ S,
    const float* __restrict__ rel, const float* __restrict__ geod,
    const int* __restrict__ idx, const float* __restrict__ rowdat,
    u16* __restrict__ agg)
{
  __shared__ float qs[4][256];
  __shared__ float ss[4][64];
  int w = threadIdx.x >> 6, lane = threadIdx.x & 63;
  int r = blockIdx.x * 4 + w;
  int b = r >> 14, n = r & (NB - 1);

  {
    ushort4 q4 = *(const ushort4*)(q + (size_t)r * DD + lane * 4);
    qs[w][lane * 4 + 0] = b2f(q4.x) * 0.0625f;
    qs[w][lane * 4 + 1] = b2f(q4.y) * 0.0625f;
    qs[w][lane * 4 + 2] = b2f(q4.z) * 0.0625f;
    qs[w][lane * 4 + 3] = b2f(q4.w) * 0.0625f;
    ss[w][lane] = S[(size_t)r * SDD + lane];
  }
  __syncthreads();

  int g = lane >> 2, sub = lane & 3;
  int nbr = idx[n * 16 + g];
  size_t gidx = ((size_t)b << 14) + nbr;

  const u16* krow = k + gidx * DD;
  float p = 0.0f;
  #pragma unroll
  for (int c = 0; c < 8; ++c) {
    int e = (c * 4 + sub) * 8;
    uint2 ka = *(const uint2*)(krow + e);
    uint2 kb2 = *(const uint2*)(krow + e + 4);
    const float* qp = &qs[w][e];
    p += blo(ka.x) * qp[0] + bhi(ka.x) * qp[1]
       + blo(ka.y) * qp[2] + bhi(ka.y) * qp[3]
       + blo(kb2.x) * qp[4] + bhi(kb2.x) * qp[5]
       + blo(kb2.y) * qp[6] + bhi(kb2.y) * qp[7];
  }
  const float* Srow = S + gidx * SDD;
  #pragma unroll
  for (int c = 0; c < 4; ++c) {
    int e = sub * 16 + c * 4;
    float4 s4 = *(const float4*)(Srow + e);
    const float* sp = &ss[w][e];
    p += s4.x * sp[0] + s4.y * sp[1] + s4.z * sp[2] + s4.w * sp[3];
  }
  p += __shfl_xor(p, 1);
  p += __shfl_xor(p, 2);

  const float* rd = rowdat + (size_t)r * 8;
  float A00 = rd[0], A01 = rd[1], A11 = rd[2];
  float g0 = rd[3], g1 = rd[4], g2 = rd[5];
  float r0 = rel[(n * 16 + g) * 2];
  float r1 = rel[(n * 16 + g) * 2 + 1];
  float ge = geod[n * 16 + g];
  float rAr = A00 * r0 * r0 + 2.0f * A01 * r0 * r1 + A11 * r1 * r1;
  float prior = expf(-ge * ge * (1.0f / 2.25f));
  float lg = p - 0.25f * ge;
  { float s = 0.25f + 0.2f  * ge; float s2 = fmaxf(s * s, 1e-6f);
    lg += g0 * (-rAr / s2 + 0.7f * prior + (ge > 1.5f ? -10000.0f : 0.0f)); }
  { float s = 0.35f + 0.2f  * ge; float s2 = fmaxf(s * s, 1e-6f);
    lg += g1 * (-rAr / s2 + 0.5f * prior + (ge > 2.5f ? -10000.0f : 0.0f)); }
  { float s = 0.55f + 0.25f * ge; float s2 = fmaxf(s * s, 1e-6f);
    lg += g2 * (-rAr / s2 + 0.3f * prior + (ge > 4.0f ? -10000.0f : 0.0f)); }

  float m = lg;
  m = fmaxf(m, __shfl_xor(m, 4));
  m = fmaxf(m, __shfl_xor(m, 8));
  m = fmaxf(m, __shfl_xor(m, 16));
  m = fmaxf(m, __shfl_xor(m, 32));
  float e = expf(lg - m);
  float sm = e;
  sm += __shfl_xor(sm, 4);
  sm += __shfl_xor(sm, 8);
  sm += __shfl_xor(sm, 16);
  sm += __shfl_xor(sm, 32);
  float att = e / sm;

  float a0 = 0.f, a1 = 0.f, a2 = 0.f, a3 = 0.f;
  size_t bbase = (size_t)b << 14;
  #pragma unroll
  for (int kk = 0; kk < 16; ++kk) {
    float akk = __shfl(att, kk * 4);
    int nb2 = __shfl(nbr, kk * 4);
    const u16* vrow = v + (bbase + nb2) * DD;
    uint2 v4 = *(const uint2*)(vrow + lane * 4);
    a0 += akk * blo(v4.x);
    a1 += akk * bhi(v4.x);
    a2 += akk * blo(v4.y);
    a3 += akk * bhi(v4.y);
  }
  *(ushort4*)(agg + (size_t)r * DD + lane * 4) =
      make_ushort4(f2b(a0), f2b(a1), f2b(a2), f2b(a3));
}

// ---------------------------------------------------------------------------
// Wo GEMM + residual + LayerNorm fused. C[128x256]/block (grid 512), 4 waves.
// ---------------------------------------------------------------------------
__global__ __launch_bounds__(256) void k_mfma_out_ln(
    const u16* __restrict__ A, const u16* __restrict__ BT,
    const float* __restrict__ bo, const float* __restrict__ zres,
    const float* __restrict__ lng, const float* __restrict__ lnb,
    float* __restrict__ outp)
{
  __shared__ u16 As[128 * 64];
  __shared__ u16 Bs[256 * 64];
  int t = threadIdx.x, wv = t >> 6, lane = t & 63;
  int m0 = blockIdx.x * 128;
  int wm = wv * 32;
  int quad = lane >> 4, l15 = lane & 15;
  int srow = lane >> 3, scol = (lane & 7) * 8;
  f32x4 acc[2][16] = {};
  for (int kc = 0; kc < 256; kc += 64) {
    if (kc) __syncthreads();
    #pragma unroll
    for (int it = 0; it < 4; ++it) {
      int c = it * 4 + wv;
      gll16(A + (size_t)(m0 + c * 8 + srow) * 256 + kc + scol, As + c * 512);
    }
    #pragma unroll
    for (int it = 0; it < 8; ++it) {
      int c = it * 4 + wv;
      gll16(BT + (size_t)(c * 8 + srow) * 256 + kc + scol, Bs + c * 512);
    }
    __syncthreads();
    #pragma unroll
    for (int ks = 0; ks < 64; ks += 32) {
      short8 af[2], bfr[16];
      #pragma unroll
      for (int mi = 0; mi < 2; ++mi)
        af[mi] = *(const short8*)&As[(wm + mi * 16 + l15) * 64 + ks + quad * 8];
      #pragma unroll
      for (int ni = 0; ni < 16; ++ni)
        bfr[ni] = *(const short8*)&Bs[(ni * 16 + l15) * 64 + ks + quad * 8];
      #pragma unroll
      for (int mi = 0; mi < 2; ++mi)
        #pragma unroll
        for (int ni = 0; ni < 16; ++ni)
          acc[mi][ni] = __builtin_amdgcn_mfma_f32_16x16x32_bf16(
              af[mi], bfr[ni], acc[mi][ni], 0, 0, 0);
    }
  }
  float lg_[16], lb_[16], bo_[16];
  #pragma unroll
  for (int ni = 0; ni < 16; ++ni) {
    int col = ni * 16 + l15;
    lg_[ni] = lng[col]; lb_[ni] = lnb[col]; bo_[ni] = bo[col];
  }
  #pragma unroll
  for (int mi = 0; mi < 2; ++mi) {
    #pragma unroll
    for (int rr = 0; rr < 4; ++rr) {
      int row = m0 + wm + mi * 16 + quad * 4 + rr;
      float x[16];
      float s = 0.0f, sq = 0.0f;
      #pragma unroll
      for (int ni = 0; ni < 16; ++ni) {
        int col = ni * 16 + l15;
        float v = acc[mi][ni][rr] + bo_[ni] + zres[(size_t)row * 256 + col];
        x[ni] = v; s += v; sq += v * v;
      }
      #pragma unroll
      for (int o = 1; o < 16; o <<= 1) {
        s += __shfl_xor(s, o);
        sq += __shfl_xor(sq, o);
      }
      float mu = s * (1.0f / 256.0f);
      float var = sq * (1.0f / 256.0f) - mu * mu;
      float rstd = rsqrtf(var + 1e-5f);
      #pragma unroll
      for (int ni = 0; ni < 16; ++ni) {
        int col = ni * 16 + l15;
        outp[(size_t)row * 256 + col] = lg_[ni] * (x[ni] - mu) * rstd + lb_[ni];
      }
    }
  }
}

// ---------------------------------------------------------------------------
// TV regularizer over anorm (rowdat slot 6).
// ---------------------------------------------------------------------------
__global__ __launch_bounds__(256) void k_tv(
    const float* __restrict__ rowdat, float* __restrict__ sums)
{
  int gid = blockIdx.x * blockDim.x + threadIdx.x;
  int stride = gridDim.x * blockDim.x;
  float dy = 0.0f, dx = 0.0f;
  for (int e = gid; e < 4 * 127 * 128; e += stride) {
    int bb = e / 16256; int rem = e % 16256;
    int i = rem >> 7; int jj = rem & 127;
    int base = bb * 16384 + i * 128 + jj;
    dy += fabsf(rowdat[(size_t)(base + 128) * 8 + 6] - rowdat[(size_t)base * 8 + 6]);
  }
  for (int e = gid; e < 4 * 128 * 127; e += stride) {
    int bb = e / 16256; int rem = e % 16256;
    int i = rem / 127; int jj = rem % 127;
    int base = bb * 16384 + i * 128 + jj;
    dx += fabsf(rowdat[(size_t)(base + 1) * 8 + 6] - rowdat[(size_t)base * 8 + 6]);
  }
  #pragma unroll
  for (int o = 32; o; o >>= 1) { dy += __shfl_down(dy, o); dx += __shfl_down(dx, o); }
  if ((threadIdx.x & 63) == 0) {
    atomicAdd(&sums[0], dy);
    atomicAdd(&sums[1], dx);
  }
}

__global__ void k_reg(const float* __restrict__ sums, float* __restrict__ out)
{
  if (threadIdx.x == 0 && blockIdx.x == 0) {
    out[16777216] = 0.001f * (sums[0] + sums[1]) * (1.0f / 65024.0f);
  }
}

// ---------------------------------------------------------------------------
extern "C" void kernel_launch(void* const* d_in, const int* in_sizes, int n_in,
                              void* d_out, int out_size, void* d_ws, size_t ws_size,
                              hipStream_t stream)
{
  const float* z    = (const float*)d_in[0];
  const float* S    = (const float*)d_in[1];
  const float* rel  = (const float*)d_in[2];
  const float* geod = (const float*)d_in[3];
  const int*   idx  = (const int*)d_in[4];
  const float* Wq = (const float*)d_in[5];  const float* bq = (const float*)d_in[6];
  const float* Wk = (const float*)d_in[7];  const float* bk = (const float*)d_in[8];
  const float* Wv = (const float*)d_in[9];  const float* bv = (const float*)d_in[10];
  const float* Wo = (const float*)d_in[11]; const float* bo = (const float*)d_in[12];
  const float* lng = (const float*)d_in[13]; const float* lnb = (const float*)d_in[14];
  const float* Ws1 = (const float*)d_in[15]; const float* bs1 = (const float*)d_in[16];
  const float* Ws2 = (const float*)d_in[17]; const float* bs2 = (const float*)d_in[18];
  const float* Wzg = (const float*)d_in[19]; const float* bzg = (const float*)d_in[20];
  const float* Wph = (const float*)d_in[21]; const float* bph = (const float*)d_in[22];
  const float* Wsg = (const float*)d_in[23]; const float* bsg = (const float*)d_in[24];

  char* ws = (char*)d_ws;
  u16* zb = (u16*)ws;  ws += 33554432;          // z bf16; ALIASED as agg after qkv GEMM
  u16* qb = (u16*)ws;  ws += 33554432;
  u16* kb = (u16*)ws;  ws += 33554432;
  u16* vb = (u16*)ws;  ws += 33554432;
  u16* WqkvT = (u16*)ws; ws += 458752;          // 896*256 bf16
  u16* WoT   = (u16*)ws; ws += 131072;
  float* biasq = (float*)ws; ws += 3136;        // 784 f32
  float* ze    = (float*)ws; ws += 4194304;     // 65536*16 f32
  float* rowdat = (float*)ws; ws += 2097152;    // 65536*8 f32 (slot6 = anorm)
  float* sums   = (float*)ws;
  u16* ab = zb;                                 // alias: zb dead after qkv GEMM

  float* outp = (float*)d_out;

  hipMemsetAsync(sums, 0, 8, stream);
  k_prep_w<<<256, 256, 0, stream>>>(Wq, Wk, Wv, Wo, Wzg, bq, bk, bv, bzg,
                                    WqkvT, WoT, biasq);
  k_pre<<<NROWS / 4, 256, 0, stream>>>(z, S, zb, rowdat);
  k_mfma_qkv<<<dim3(512, 7), 256, 0, stream>>>(zb, WqkvT, biasq, qb, kb, vb, ze);
  k_post<<<NROWS / 16, 256, 0, stream>>>(ze, Ws1, bs1, Ws2, bs2,
                                         Wph, bph, Wsg, bsg, rowdat);
  k_attn<<<NROWS / 4, 256, 0, stream>>>(qb, kb, vb, S, rel, geod, idx, rowdat, ab);
  k_mfma_out_ln<<<512, 256, 0, stream>>>(ab, WoT, bo, z, lng, lnb, outp);
  k_tv<<<256, 256, 0, stream>>>(rowdat, sums);
  k_reg<<<1, 64, 0, stream>>>(sums, outp);
}